// Round 7
// baseline (315.651 us; speedup 1.0000x reference)
//
#include <hip/hip_runtime.h>
#include <math.h>

#define HIDDEN 1024
#define SEQ    2048
#define NHEAD  16
#define HDIM   64
#define ROWS   (2 * SEQ)

typedef float  floatx4  __attribute__((ext_vector_type(4)));
typedef float  floatx16 __attribute__((ext_vector_type(16)));
typedef __bf16 bf16x8   __attribute__((ext_vector_type(8)));
typedef __bf16 bf16x4   __attribute__((ext_vector_type(4)));

#define AS1(p) ((const __attribute__((address_space(1))) void*)(p))
#define AS3(p) ((__attribute__((address_space(3))) void*)(p))

// swizzled byte-chunk offset (in elements): 16B chunks XOR'd by row&7 (attn)
#define SWZ(row, chunk) ((((chunk) ^ ((row) & 7)) * 8))

// XCD-aware bijective block swizzle (T1). Requires nwg % 8 == 0.
// Consecutive chunk of nwg/8 linear ids -> one XCD; shares B-panels in L2.
__device__ __forceinline__ void xcd_swz(int &bx, int &by) {
    int gx = gridDim.x;
    int nwg = gx * gridDim.y;
    int lin = by * gx + bx;
    int s = (lin & 7) * (nwg >> 3) + (lin >> 3);
    bx = s % gx;
    by = s / gx;
}

// ---------------------------------------------------------------------------
// Prep launch: 6 weight converts + LayerNorm1, one kernel.
// QKV / W1 / W2 -> PLAIN transposed bf16 Bt[n][k] (for the 256-tile core).
// Wo           -> fragment-major BtF (legacy 128-tile core).
// ---------------------------------------------------------------------------
__global__ __launch_bounds__(256) void prep_all(const float* __restrict__ Wq,
                                                const float* __restrict__ Wk,
                                                const float* __restrict__ Wv,
                                                const float* __restrict__ Wo,
                                                const float* __restrict__ W1,
                                                const float* __restrict__ W2,
                                                __bf16* __restrict__ BtQKV,
                                                __bf16* __restrict__ BtO,
                                                __bf16* __restrict__ Bt1,
                                                __bf16* __restrict__ Bt2,
                                                const float* __restrict__ emb,
                                                const float* __restrict__ g1,
                                                const float* __restrict__ be1,
                                                __bf16* __restrict__ h) {
    int id = blockIdx.x;
    int tid = threadIdx.x;
    if (id >= 12288) {
        // ---- LayerNorm1 row ----
        int row = id - 12288;
        size_t i = (size_t)row * HIDDEN + tid * 4;
        float4 v = *(const float4*)(emb + i);
        float s  = v.x + v.y + v.z + v.w;
        float s2 = v.x * v.x + v.y * v.y + v.z * v.z + v.w * v.w;
#pragma unroll
        for (int off = 1; off < 64; off <<= 1) {
            s  += __shfl_xor(s, off, 64);
            s2 += __shfl_xor(s2, off, 64);
        }
        __shared__ float red[8];
        int wid = tid >> 6;
        if ((tid & 63) == 0) { red[wid] = s; red[wid + 4] = s2; }
        __syncthreads();
        s  = red[0] + red[1] + red[2] + red[3];
        s2 = red[4] + red[5] + red[6] + red[7];
        float mu  = s * (1.0f / HIDDEN);
        float var = fmaxf(s2 * (1.0f / HIDDEN) - mu * mu, 0.0f);
        float inv = rsqrtf(var + 1e-5f);
        float4 gv = *(const float4*)(g1 + tid * 4);
        float4 bv = *(const float4*)(be1 + tid * 4);
        bf16x4 o;
        o[0] = (__bf16)((v.x - mu) * inv * gv.x + bv.x);
        o[1] = (__bf16)((v.y - mu) * inv * gv.y + bv.y);
        o[2] = (__bf16)((v.z - mu) * inv * gv.z + bv.z);
        o[3] = (__bf16)((v.w - mu) * inv * gv.w + bv.w);
        *(bf16x4*)(h + i) = o;
        return;
    }
    // ---- weight convert tile (32x32) ----
    __shared__ float t[32][33];
    const float* in; __bf16* out; int K, N, nt, kt;
    if (id < 4096) {
        int job = id >> 10, tt = id & 1023;
        nt = tt & 31; kt = tt >> 5; K = 1024; N = 1024;
        if (job == 0)      { in = Wq; out = BtQKV; }
        else if (job == 1) { in = Wk; out = BtQKV + 1024 * 1024; }
        else if (job == 2) { in = Wv; out = BtQKV + 2 * 1024 * 1024; }
        else               { in = Wo; out = BtO; }
    } else if (id < 8192) {
        int tt = id - 4096;
        nt = tt & 127; kt = tt >> 7; K = 1024; N = 4096; in = W1; out = Bt1;
    } else {
        int tt = id - 8192;
        nt = tt & 31; kt = tt >> 5; K = 4096; N = 1024; in = W2; out = Bt2;
    }
    bool frag = (id >= 3072 && id < 4096);    // only Wo keeps fragment-major
    int n0 = nt * 32, k0 = kt * 32;
    int r  = tid >> 3;             // n within tile
    int c4 = (tid & 7) * 4;        // k run of 4
    float4 v = *(const float4*)(in + (size_t)(k0 + r) * N + n0 + c4);
    t[r][c4 + 0] = v.x; t[r][c4 + 1] = v.y; t[r][c4 + 2] = v.z; t[r][c4 + 3] = v.w;
    __syncthreads();
    bf16x4 o;
    o[0] = (__bf16)t[c4 + 0][r];
    o[1] = (__bf16)t[c4 + 1][r];
    o[2] = (__bf16)t[c4 + 2][r];
    o[3] = (__bf16)t[c4 + 3][r];
    int n = n0 + r, k = k0 + c4;
    if (!frag) {
        *(bf16x4*)(out + (size_t)n * K + k) = o;
    } else {
        size_t blk = (size_t)(n >> 5) * (K >> 4) + (k >> 4);
        int ln = ((k >> 3) & 1) * 32 + (n & 31);
        *(bf16x4*)(out + blk * 512 + ln * 8 + (k & 7)) = o;
    }
}

// ---------------------------------------------------------------------------
// Fused Wo-split-K(x2) reduction + residual + LayerNorm2.
// ---------------------------------------------------------------------------
__global__ __launch_bounds__(256) void red_wo_ln(const float* __restrict__ emb,
                                                 const __bf16* __restrict__ p0,
                                                 const __bf16* __restrict__ p1,
                                                 const float* __restrict__ g,
                                                 const float* __restrict__ beta,
                                                 float* __restrict__ out,
                                                 __bf16* __restrict__ h2) {
    int row = blockIdx.x;
    int tid = threadIdx.x;
    size_t i = (size_t)row * HIDDEN + tid * 4;
    float4 e = *(const float4*)(emb + i);
    bf16x4 a = *(const bf16x4*)(p0 + i);
    bf16x4 b = *(const bf16x4*)(p1 + i);
    float4 v;
    v.x = e.x + (float)a[0] + (float)b[0];
    v.y = e.y + (float)a[1] + (float)b[1];
    v.z = e.z + (float)a[2] + (float)b[2];
    v.w = e.w + (float)a[3] + (float)b[3];
    *(float4*)(out + i) = v;

    float s  = v.x + v.y + v.z + v.w;
    float s2 = v.x * v.x + v.y * v.y + v.z * v.z + v.w * v.w;
#pragma unroll
    for (int off = 1; off < 64; off <<= 1) {
        s  += __shfl_xor(s, off, 64);
        s2 += __shfl_xor(s2, off, 64);
    }
    __shared__ float red[8];
    int wid = tid >> 6;
    if ((tid & 63) == 0) { red[wid] = s; red[wid + 4] = s2; }
    __syncthreads();
    s  = red[0] + red[1] + red[2] + red[3];
    s2 = red[4] + red[5] + red[6] + red[7];
    float mu  = s * (1.0f / HIDDEN);
    float var = fmaxf(s2 * (1.0f / HIDDEN) - mu * mu, 0.0f);
    float inv = rsqrtf(var + 1e-5f);
    float4 gv = *(const float4*)(g + tid * 4);
    float4 bv = *(const float4*)(beta + tid * 4);
    bf16x4 o;
    o[0] = (__bf16)((v.x - mu) * inv * gv.x + bv.x);
    o[1] = (__bf16)((v.y - mu) * inv * gv.y + bv.y);
    o[2] = (__bf16)((v.z - mu) * inv * gv.z + bv.z);
    o[3] = (__bf16)((v.w - mu) * inv * gv.w + bv.w);
    *(bf16x4*)(h2 + i) = o;
}

// ---------------------------------------------------------------------------
// W2 reduction: out += p0+p1+p2+p3 + b2[col]
// ---------------------------------------------------------------------------
__global__ __launch_bounds__(256) void red_w2(const __bf16* __restrict__ p0,
                                              const __bf16* __restrict__ p3,
                                              const float* __restrict__ b2,
                                              float* __restrict__ out,
                                              int N) {
    size_t i = ((size_t)blockIdx.x * 256 + threadIdx.x) * 8;
    const size_t MN = (size_t)ROWS * HIDDEN;
    bf16x8 a = *(const bf16x8*)(p0 + i);
    bf16x8 b = *(const bf16x8*)(p0 + MN + i);
    bf16x8 c = *(const bf16x8*)(p0 + 2 * MN + i);
    bf16x8 d = *(const bf16x8*)(p3 + i);
    int col = (int)(i & (size_t)(N - 1));
    float4 bb0 = *(const float4*)(b2 + col);
    float4 bb1 = *(const float4*)(b2 + col + 4);
    float4 o0 = *(const float4*)(out + i);
    float4 o1 = *(const float4*)(out + i + 4);
    o0.x += (float)a[0] + (float)b[0] + (float)c[0] + (float)d[0] + bb0.x;
    o0.y += (float)a[1] + (float)b[1] + (float)c[1] + (float)d[1] + bb0.y;
    o0.z += (float)a[2] + (float)b[2] + (float)c[2] + (float)d[2] + bb0.z;
    o0.w += (float)a[3] + (float)b[3] + (float)c[3] + (float)d[3] + bb0.w;
    o1.x += (float)a[4] + (float)b[4] + (float)c[4] + (float)d[4] + bb1.x;
    o1.y += (float)a[5] + (float)b[5] + (float)c[5] + (float)d[5] + bb1.y;
    o1.z += (float)a[6] + (float)b[6] + (float)c[6] + (float)d[6] + bb1.z;
    o1.w += (float)a[7] + (float)b[7] + (float)c[7] + (float)d[7] + bb1.w;
    *(float4*)(out + i)     = o0;
    *(float4*)(out + i + 4) = o1;
}

// ---------------------------------------------------------------------------
// Legacy 128x128 MFMA core (Wo split-K only — short-K regime winner).
// ---------------------------------------------------------------------------
__device__ __forceinline__ void mfma_core128(const __bf16* __restrict__ A,
                                             const __bf16* __restrict__ BtF,
                                             int Kstride, int kbase, int Klen,
                                             int m0, int n0, int tid,
                                             floatx16 (&acc)[2][2]) {
    __shared__ __bf16 As[2 * 128 * 32];
    const int BUF = 128 * 32;
    int lane = tid & 63;
    int wave = tid >> 6;
    int wr = wave >> 1, wc = wave & 1;

    int sr = lane >> 2;
    int sk = 8 * ((lane & 3) ^ ((sr >> 1) & 3));
    const __bf16* ga0 = A + (size_t)(m0 + wave * 16 + sr) * Kstride + kbase + sk;
    const __bf16* ga1 = ga0 + (size_t)64 * Kstride;
    __bf16* la0 = &As[wave * 512];
    __bf16* la1 = &As[2048 + wave * 512];

    int fm = lane & 31;
    int gswz = (lane >> 1) & 3;
    int slot0 = ((lane >> 5) + 0) ^ gswz;
    int slot1 = ((lane >> 5) + 2) ^ gswz;

    const __bf16* bb = BtF + ((size_t)((n0 >> 5) + wc * 2) * (Kstride >> 4)) * 512
                     + (size_t)lane * 8;
    const size_t jstr = (size_t)(Kstride >> 4) * 512;
    int ci0 = kbase >> 4;

    __builtin_amdgcn_global_load_lds(AS1(ga0), AS3(la0), 16, 0, 0);
    __builtin_amdgcn_global_load_lds(AS1(ga1), AS3(la1), 16, 0, 0);
    bf16x8 bcur[2][2], bnxt[2][2];
#pragma unroll
    for (int j = 0; j < 2; j++)
#pragma unroll
        for (int t = 0; t < 2; t++)
            bcur[j][t] = *(const bf16x8*)(bb + j * jstr + (size_t)(ci0 + t) * 512);

    int buf = 0;
    for (int k0 = 0; k0 < Klen; k0 += 32, buf ^= 1) {
        __syncthreads();
        if (k0 + 32 < Klen) {
            int nb = (buf ^ 1) * BUF;
            __builtin_amdgcn_global_load_lds(AS1(ga0 + k0 + 32), AS3(la0 + nb), 16, 0, 0);
            __builtin_amdgcn_global_load_lds(AS1(ga1 + k0 + 32), AS3(la1 + nb), 16, 0, 0);
            int ci = ci0 + ((k0 + 32) >> 4);
#pragma unroll
            for (int j = 0; j < 2; j++)
#pragma unroll
                for (int t = 0; t < 2; t++)
                    bnxt[j][t] = *(const bf16x8*)(bb + j * jstr + (size_t)(ci + t) * 512);
        }
        const __bf16* Ab = As + buf * BUF;
        bf16x8 af[2][2];
#pragma unroll
        for (int i = 0; i < 2; i++) {
            const __bf16* rp = Ab + (size_t)(wr * 64 + i * 32 + fm) * 32;
            af[i][0] = *(const bf16x8*)(rp + slot0 * 8);
            af[i][1] = *(const bf16x8*)(rp + slot1 * 8);
        }
#pragma unroll
        for (int t = 0; t < 2; t++)
#pragma unroll
            for (int i = 0; i < 2; i++)
#pragma unroll
                for (int j = 0; j < 2; j++)
                    acc[i][j] = __builtin_amdgcn_mfma_f32_32x32x16_bf16(
                        af[i][t], bcur[j][t], acc[i][j], 0, 0, 0);
#pragma unroll
        for (int j = 0; j < 2; j++)
#pragma unroll
            for (int t = 0; t < 2; t++)
                bcur[j][t] = bnxt[j][t];
    }
}

// ---------------------------------------------------------------------------
// Split-K GEMM on the legacy core (Wo only; z in {0,1}). + XCD swizzle.
// ---------------------------------------------------------------------------
__global__ __launch_bounds__(256) void mgemm_sk(const __bf16* __restrict__ A,
                                                const __bf16* __restrict__ BtF,
                                                __bf16* __restrict__ P0,
                                                __bf16* __restrict__ P3,
                                                int M, int N, int Kstride, int Klen) {
    int z = blockIdx.z;
    __bf16* C = (z == 3) ? P3 : (P0 + (size_t)z * M * N);
    int tid = threadIdx.x;
    int lane = tid & 63;
    int wave = tid >> 6;
    int bx = blockIdx.x, by = blockIdx.y;
    xcd_swz(bx, by);
    int m0 = bx * 128, n0 = by * 128;
    int wr = wave >> 1, wc = wave & 1;
    floatx16 acc[2][2] = {};
    mfma_core128(A, BtF, Kstride, z * Klen, Klen, m0, n0, tid, acc);

#pragma unroll
    for (int i = 0; i < 2; i++) {
#pragma unroll
        for (int j = 0; j < 2; j++) {
            int col  = n0 + wc * 64 + j * 32 + (lane & 31);
            int rowb = m0 + wr * 64 + i * 32 + 4 * (lane >> 5);
#pragma unroll
            for (int reg = 0; reg < 16; reg++) {
                int row = rowb + (reg & 3) + 8 * (reg >> 2);
                C[(size_t)row * N + col] = (__bf16)acc[i][j][reg];
            }
        }
    }
}

// ---------------------------------------------------------------------------
// 256x256 MFMA core, BK=32, 512 threads = 8 waves (2M x 4N), ring-4 LDS,
// counted-vmcnt phase schedule. (verified R2)
// ---------------------------------------------------------------------------
template <int KLEN>
__device__ __forceinline__ void mfma_core256(const __bf16* __restrict__ A,
                                             const __bf16* __restrict__ Bt,
                                             int Kstride, int kbase,
                                             int m0, int n0, int tid,
                                             floatx16 (&acc)[4][2]) {
    __shared__ __bf16 lds[8 * 8192];          // 128 KiB
    const int NT = KLEN >> 5;                 // K-tiles of 32 (NT >= 3)
    int l = tid & 63;
    int w = tid >> 6;
    int wr = w >> 2, wc = w & 3;

    int lr  = l >> 2;                                 // row within group
    int lcf = ((l & 3) ^ ((l >> 3) & 3)) * 8;         // pre-swizzled src chunk
    const __bf16* gA0 = A  + (size_t)(m0 + (w * 2 + 0) * 16 + lr) * Kstride + kbase + lcf;
    const __bf16* gA1 = A  + (size_t)(m0 + (w * 2 + 1) * 16 + lr) * Kstride + kbase + lcf;
    const __bf16* gB0 = Bt + (size_t)(n0 + (w * 2 + 0) * 16 + lr) * Kstride + kbase + lcf;
    const __bf16* gB1 = Bt + (size_t)(n0 + (w * 2 + 1) * 16 + lr) * Kstride + kbase + lcf;
    __bf16* lA0 = lds + (w * 2 + 0) * 512;
    __bf16* lA1 = lds + (w * 2 + 1) * 512;
    __bf16* lB0 = lA0 + 32768;
    __bf16* lB1 = lA1 + 32768;

#define STG_A(tt) do { int b_ = (tt) & 3; int ko_ = (tt) * 32;                          \
    __builtin_amdgcn_global_load_lds(AS1(gA0 + ko_), AS3(lA0 + b_ * 8192), 16, 0, 0);   \
    __builtin_amdgcn_global_load_lds(AS1(gA1 + ko_), AS3(lA1 + b_ * 8192), 16, 0, 0); } while (0)
#define STG_B(tt) do { int b_ = (tt) & 3; int ko_ = (tt) * 32;                          \
    __builtin_amdgcn_global_load_lds(AS1(gB0 + ko_), AS3(lB0 + b_ * 8192), 16, 0, 0);   \
    __builtin_amdgcn_global_load_lds(AS1(gB1 + ko_), AS3(lB1 + b_ * 8192), 16, 0, 0); } while (0)

    STG_A(0); STG_B(0);
    STG_A(1); STG_B(1);
    STG_A(2); STG_B(2);

    int fm = l & 31, cc = l >> 5;
    int sw = (fm >> 1) & 3;
    int pc0 = ((0 + cc) ^ sw) * 8;
    int pc1 = ((2 + cc) ^ sw) * 8;
    int aB  = (wr * 128 + fm) * 32;
    int bB  = (wc * 64 + fm) * 32 + 32768;

    for (int t = 0; t < NT; ++t) {
        if (t + 3 <= NT)
            asm volatile("s_waitcnt vmcnt(8)\n\ts_barrier" ::: "memory");
        else if (t + 2 <= NT)
            asm volatile("s_waitcnt vmcnt(4)\n\ts_barrier" ::: "memory");
        else
            asm volatile("s_waitcnt vmcnt(0)\n\ts_barrier" ::: "memory");

        const __bf16* base = lds + (t & 3) * 8192;

        bf16x8 a0[2][2], bfr[2][2];
        a0[0][0]  = *(const bf16x8*)(base + aB + 0 * 1024 + pc0);
        a0[0][1]  = *(const bf16x8*)(base + aB + 0 * 1024 + pc1);
        a0[1][0]  = *(const bf16x8*)(base + aB + 1 * 1024 + pc0);
        a0[1][1]  = *(const bf16x8*)(base + aB + 1 * 1024 + pc1);
        bfr[0][0] = *(const bf16x8*)(base + bB + 0 * 1024 + pc0);
        bfr[0][1] = *(const bf16x8*)(base + bB + 0 * 1024 + pc1);
        bfr[1][0] = *(const bf16x8*)(base + bB + 1 * 1024 + pc0);
        bfr[1][1] = *(const bf16x8*)(base + bB + 1 * 1024 + pc1);
        if (t + 3 < NT) STG_A(t + 3);
        __builtin_amdgcn_s_barrier();
        asm volatile("s_waitcnt lgkmcnt(0)" ::: "memory");
        __builtin_amdgcn_sched_barrier(0);
        __builtin_amdgcn_s_setprio(1);
#pragma unroll
        for (int u = 0; u < 2; ++u)
#pragma unroll
            for (int i = 0; i < 2; ++i)
#pragma unroll
                for (int j = 0; j < 2; ++j)
                    acc[i][j] = __builtin_amdgcn_mfma_f32_32x32x16_bf16(
                        a0[i][u], bfr[j][u], acc[i][j], 0, 0, 0);
        __builtin_amdgcn_s_setprio(0);

        bf16x8 a1[2][2];
        a1[0][0] = *(const bf16x8*)(base + aB + 2 * 1024 + pc0);
        a1[0][1] = *(const bf16x8*)(base + aB + 2 * 1024 + pc1);
        a1[1][0] = *(const bf16x8*)(base + aB + 3 * 1024 + pc0);
        a1[1][1] = *(const bf16x8*)(base + aB + 3 * 1024 + pc1);
        if (t + 3 < NT) STG_B(t + 3);
        __builtin_amdgcn_s_barrier();
        asm volatile("s_waitcnt lgkmcnt(0)" ::: "memory");
        __builtin_amdgcn_sched_barrier(0);
        __builtin_amdgcn_s_setprio(1);
#pragma unroll
        for (int u = 0; u < 2; ++u)
#pragma unroll
            for (int i = 0; i < 2; ++i)
#pragma unroll
                for (int j = 0; j < 2; ++j)
                    acc[2 + i][j] = __builtin_amdgcn_mfma_f32_32x32x16_bf16(
                        a1[i][u], bfr[j][u], acc[2 + i][j], 0, 0, 0);
        __builtin_amdgcn_s_setprio(0);
    }
#undef STG_A
#undef STG_B
}

// ---------------------------------------------------------------------------
// 256-tile GEMM with bias/ReLU epilogue (W1). + XCD swizzle.
// ---------------------------------------------------------------------------
template <bool BIAS, bool RELU>
__global__ __launch_bounds__(512, 2) void mgemm256(const __bf16* __restrict__ A,
                                                   const __bf16* __restrict__ Bt,
                                                   const float* __restrict__ bias,
                                                   __bf16* __restrict__ C,
                                                   int N, int Kstride) {
    int tid = threadIdx.x;
    int l = tid & 63, w = tid >> 6;
    int wr = w >> 2, wc = w & 3;
    int bx = blockIdx.x, by = blockIdx.y;
    xcd_swz(bx, by);
    int m0 = bx * 256, n0 = by * 256;
    floatx16 acc[4][2] = {};
    mfma_core256<1024>(A, Bt, Kstride, 0, m0, n0, tid, acc);
#pragma unroll
    for (int i = 0; i < 4; ++i)
#pragma unroll
        for (int j = 0; j < 2; ++j) {
            int col  = n0 + wc * 64 + j * 32 + (l & 31);
            int rowb = m0 + wr * 128 + i * 32 + 4 * (l >> 5);
            float bv = 0.0f;
            if (BIAS) bv = bias[col];
#pragma unroll
            for (int reg = 0; reg < 16; ++reg) {
                int row = rowb + (reg & 3) + 8 * (reg >> 2);
                float v = acc[i][j][reg] + bv;
                if (RELU) v = fmaxf(v, 0.0f);
                C[(size_t)row * N + col] = (__bf16)v;
            }
        }
}

// ---------------------------------------------------------------------------
// 256-tile split-K GEMM (W2, KLEN=1024). + XCD swizzle on xy-plane.
// ---------------------------------------------------------------------------
template <int KLEN>
__global__ __launch_bounds__(512, 2) void mgemm256_sk(const __bf16* __restrict__ A,
                                                      const __bf16* __restrict__ Bt,
                                                      __bf16* __restrict__ P0,
                                                      __bf16* __restrict__ P3,
                                                      int M, int N, int Kstride) {
    int z = blockIdx.z;
    __bf16* C = (z == 3) ? P3 : (P0 + (size_t)z * M * N);
    int tid = threadIdx.x;
    int l = tid & 63, w = tid >> 6;
    int wr = w >> 2, wc = w & 3;
    int bx = blockIdx.x, by = blockIdx.y;
    xcd_swz(bx, by);
    int m0 = bx * 256, n0 = by * 256;
    floatx16 acc[4][2] = {};
    mfma_core256<KLEN>(A, Bt, Kstride, z * KLEN, m0, n0, tid, acc);
#pragma unroll
    for (int i = 0; i < 4; ++i)
#pragma unroll
        for (int j = 0; j < 2; ++j) {
            int col  = n0 + wc * 64 + j * 32 + (l & 31);
            int rowb = m0 + wr * 128 + i * 32 + 4 * (l >> 5);
#pragma unroll
            for (int reg = 0; reg < 16; ++reg) {
                int row = rowb + (reg & 3) + 8 * (reg >> 2);
                C[(size_t)row * N + col] = (__bf16)acc[i][j][reg];
            }
        }
}

// ---------------------------------------------------------------------------
// 256-tile QKV GEMM: q,k columns to qkv[4096][3072]; v columns written only
// as transposed Vt[bh][d][T]. + XCD swizzle.
// ---------------------------------------------------------------------------
__global__ __launch_bounds__(512, 2) void mgemm256_qkv(const __bf16* __restrict__ A,
                                                       const __bf16* __restrict__ Bt,
                                                       __bf16* __restrict__ C,
                                                       __bf16* __restrict__ Vt) {
    const int N = 3072;
    int tid = threadIdx.x;
    int l = tid & 63, w = tid >> 6;
    int wr = w >> 2, wc = w & 3;
    int bx = blockIdx.x, by = blockIdx.y;
    xcd_swz(bx, by);
    int m0 = bx * 256, n0 = by * 256;
    floatx16 acc[4][2] = {};
    mfma_core256<1024>(A, Bt, 1024, 0, m0, n0, tid, acc);
#pragma unroll
    for (int i = 0; i < 4; ++i)
#pragma unroll
        for (int j = 0; j < 2; ++j) {
            int col  = n0 + wc * 64 + j * 32 + (l & 31);
            int rowb = m0 + wr * 128 + i * 32 + 4 * (l >> 5);
            if (col < 2048) {
#pragma unroll
                for (int reg = 0; reg < 16; ++reg) {
                    int row = rowb + (reg & 3) + 8 * (reg >> 2);
                    C[(size_t)row * N + col] = (__bf16)acc[i][j][reg];
                }
            } else {
                int vcol = col - 2048;
                int hh = vcol >> 6, dd = vcol & 63;
#pragma unroll
                for (int rq = 0; rq < 4; rq++) {
                    int row0 = rowb + 8 * rq;
                    int bb = row0 >> 11;
                    int tt = row0 & 2047;
                    bf16x4 pack;
                    pack[0] = (__bf16)acc[i][j][4 * rq + 0];
                    pack[1] = (__bf16)acc[i][j][4 * rq + 1];
                    pack[2] = (__bf16)acc[i][j][4 * rq + 2];
                    pack[3] = (__bf16)acc[i][j][4 * rq + 3];
                    *(bf16x4*)&Vt[(((size_t)bb * 16 + hh) * 64 + dd) * SEQ + tt] = pack;
                }
            }
        }
}

// ---------------------------------------------------------------------------
// MFMA flash attention (verified R5 config, 43.8 us): single-buffered K/V,
// no-max exp2 softmax, ones-MFMA l, K/V register prefetch, setprio.
// [dbuf variant measured slower: 47.7 us R6 — do not reintroduce]
// ---------------------------------------------------------------------------
__global__ __launch_bounds__(256) void attn_mfma(const __bf16* __restrict__ qkv,
                                                 const __bf16* __restrict__ Vt,
                                                 __bf16* __restrict__ ctx) {
    __shared__ __bf16 Ks[64 * 64];
    __shared__ __bf16 Vs[64 * 64];
    __shared__ __bf16 Ps[4][16 * 64];
    const int QKVW = 3 * HIDDEN;

    int bh = blockIdx.x;
    int qt = gridDim.y - 1 - blockIdx.y;
    int b = bh >> 4, h = bh & 15;
    int tid = threadIdx.x;
    int lane = tid & 63;
    int w = tid >> 6;
    int m = lane & 15;
    int g = lane >> 4;

    const float QSC = 1.44269504f / 8.0f;
    bf16x8 qf[2];
    {
        const __bf16* Qp = qkv + (size_t)(b * SEQ + qt * 64 + w * 16 + m) * QKVW
                         + h * HDIM + g * 8;
        qf[0] = *(const bf16x8*)(Qp);
        qf[1] = *(const bf16x8*)(Qp + 32);
#pragma unroll
        for (int t = 0; t < 2; t++)
#pragma unroll
            for (int i = 0; i < 8; i++)
                qf[t][i] = (__bf16)((float)qf[t][i] * QSC);
    }

    bf16x8 onesf;
#pragma unroll
    for (int i = 0; i < 8; i++) onesf[i] = (__bf16)1.0f;

    floatx4 oacc[4] = {};
    floatx4 lacc = {};

    int srow = tid >> 2;
    int sc0  = (tid & 3) * 2;
    const __bf16* Kg = qkv + (size_t)(b * SEQ) * QKVW + HIDDEN + h * HDIM;
    const __bf16* Vg = Vt + (size_t)bh * HDIM * SEQ;

    bf16x8 pk0, pk1, pv0, pv1;
    {
        const __bf16* kp = Kg + (size_t)srow * QKVW + sc0 * 8;
        pk0 = *(const bf16x8*)kp;
        pk1 = *(const bf16x8*)(kp + 8);
        const __bf16* vp = Vg + (size_t)srow * SEQ + sc0 * 8;
        pv0 = *(const bf16x8*)vp;
        pv1 = *(const bf16x8*)(vp + 8);
    }

    for (int kt = 0; kt <= qt; kt++) {
        __syncthreads();
        *(bf16x8*)&Ks[srow * 64 + SWZ(srow, sc0)]     = pk0;
        *(bf16x8*)&Ks[srow * 64 + SWZ(srow, sc0 + 1)] = pk1;
        *(bf16x8*)&Vs[srow * 64 + SWZ(srow, sc0)]     = pv0;
        *(bf16x8*)&Vs[srow * 64 + SWZ(srow, sc0 + 1)] = pv1;
        __syncthreads();

        if (kt < qt) {
            const __bf16* kp = Kg + (size_t)((kt + 1) * 64 + srow) * QKVW + sc0 * 8;
            pk0 = *(const bf16x8*)kp;
            pk1 = *(const bf16x8*)(kp + 8);
            const __bf16* vp = Vg + (size_t)srow * SEQ + (kt + 1) * 64 + sc0 * 8;
            pv0 = *(const bf16x8*)vp;
            pv1 = *(const bf16x8*)(vp + 8);
        }

        floatx4 sacc[4] = {};
        __builtin_amdgcn_s_setprio(1);
#pragma unroll
        for (int j = 0; j < 4; j++) {
#pragma unroll
            for (int t = 0; t < 2; t++) {
                int kr = 16 * j + m;
                bf16x8 kf = *(const bf16x8*)&Ks[kr * 64 + SWZ(kr, g + 4 * t)];
                sacc[j] = __builtin_amdgcn_mfma_f32_16x16x32_bf16(
                    qf[t], kf, sacc[j], 0, 0, 0);
            }
        }
        __builtin_amdgcn_s_setprio(0);

        if (kt == qt) {
            int qlocal = w * 16 + 4 * g;
#pragma unroll
            for (int j = 0; j < 4; j++)
#pragma unroll
                for (int r = 0; r < 4; r++)
                    if (16 * j + m > qlocal + r) sacc[j][r] = -INFINITY;
        }

        __bf16* Pw = &Ps[w][0];
#pragma unroll
        for (int j = 0; j < 4; j++)
#pragma unroll
            for (int r = 0; r < 4; r++) {
                float p = exp2f(sacc[j][r]);
                int row = 4 * g + r;
                int key = 16 * j + m;
                Pw[row * 64 + SWZ(row, key >> 3) + (key & 7)] = (__bf16)p;
            }

        __builtin_amdgcn_s_setprio(1);
#pragma unroll
        for (int t = 0; t < 2; t++) {
            bf16x8 pf = *(const bf16x8*)&Pw[m * 64 + SWZ(m, g + 4 * t)];
            lacc = __builtin_amdgcn_mfma_f32_16x16x32_bf16(pf, onesf, lacc, 0, 0, 0);
#pragma unroll
            for (int jd = 0; jd < 4; jd++) {
                int vr = 16 * jd + m;
                bf16x8 vf = *(const bf16x8*)&Vs[vr * 64 + SWZ(vr, g + 4 * t)];
                oacc[jd] = __builtin_amdgcn_mfma_f32_16x16x32_bf16(
                    pf, vf, oacc[jd], 0, 0, 0);
            }
        }
        __builtin_amdgcn_s_setprio(0);
    }

#pragma unroll
    for (int r = 0; r < 4; r++) {
        float invl = 1.0f / lacc[r];
        int row = qt * 64 + w * 16 + 4 * g + r;
        __bf16* cp = ctx + (size_t)(b * SEQ + row) * HIDDEN + h * HDIM;
#pragma unroll
        for (int jd = 0; jd < 4; jd++)
            cp[16 * jd + m] = (__bf16)(oacc[jd][r] * invl);
    }
}

// ---------------------------------------------------------------------------
extern "C" void kernel_launch(void* const* d_in, const int* in_sizes, int n_in,
                              void* d_out, int out_size, void* d_ws, size_t ws_size,
                              hipStream_t stream) {
    (void)in_sizes; (void)n_in; (void)out_size; (void)ws_size;
    const float* emb = (const float*)d_in[0];
    const float* Wq  = (const float*)d_in[1];
    const float* Wk  = (const float*)d_in[2];
    const float* Wv  = (const float*)d_in[3];
    const float* Wo  = (const float*)d_in[4];
    const float* W1  = (const float*)d_in[5];
    const float* b1  = (const float*)d_in[6];
    const float* W2  = (const float*)d_in[7];
    const float* b2  = (const float*)d_in[8];
    const float* g1  = (const float*)d_in[9];
    const float* be1 = (const float*)d_in[10];
    const float* g2  = (const float*)d_in[11];
    const float* be2 = (const float*)d_in[12];
    float* out = (float*)d_out;

    // ws layout (bf16 elems; ME = 1M elems = 2MB). Total 36 ME = 72 MB.
    //   [0,4)   h (LN1) -> ctx (attn out) -> ff1 head
    //   [4,16)  qkv (q,k cols used) -> Wo partials [4,12) -> ff1
    //   [16,20) h2 -> W2 partial z0
    //   [20,24) BtQKV+BtO -> W2 partial z1
    //   [24,28) Bt1 -> W2 partial z2
    //   [28,32) Bt2 (alive through W2 gemm)
    //   [32,36) Vt -> W2 partial z3
    __bf16* wsb = (__bf16*)d_ws;
    const size_t ME = 1024 * 1024;
    __bf16* h     = wsb;
    __bf16* qkv   = wsb + 4 * ME;
    __bf16* ctx   = wsb;
    __bf16* ff1   = wsb;
    __bf16* h2    = wsb + 16 * ME;
    __bf16* BtQKV = wsb + 20 * ME;
    __bf16* BtO   = wsb + 23 * ME;
    __bf16* Bt1   = wsb + 24 * ME;
    __bf16* Bt2   = wsb + 28 * ME;
    __bf16* Vt    = wsb + 32 * ME;
    __bf16* woP   = wsb + 4 * ME;    // 2 x 4 ME
    __bf16* w2P0  = wsb + 16 * ME;   // z0..z2 contiguous (12 ME)
    __bf16* w2P3  = wsb + 32 * ME;   // z3

    prep_all<<<16384, 256, 0, stream>>>(Wq, Wk, Wv, Wo, W1, W2,
                                        BtQKV, BtO, Bt1, Bt2,
                                        emb, g1, be1, h);

    mgemm256_qkv<<<dim3(16, 12), 512, 0, stream>>>(h, BtQKV, qkv, Vt);

    attn_mfma<<<dim3(32, 32), 256, 0, stream>>>(qkv, Vt, ctx);

    // Wo split-K x2 on the legacy 128-tile core, bf16 partials
    mgemm_sk<<<dim3(32, 8, 2), 256, 0, stream>>>(
        ctx, BtO, woP, nullptr, ROWS, 1024, 1024, 512);
    red_wo_ln<<<ROWS, 256, 0, stream>>>(emb, woP, woP + 4 * ME, g2, be2, out, h2);

    mgemm256<true, true><<<dim3(16, 16), 512, 0, stream>>>(
        h2, Bt1, b1, ff1, 4096, 1024);

    // W2 split-K x4 on the 256-tile core, bf16 partials
    mgemm256_sk<1024><<<dim3(16, 4, 4), 512, 0, stream>>>(
        ff1, Bt2, w2P0, w2P3, ROWS, 1024, 4096);
    red_w2<<<2048, 256, 0, stream>>>(w2P0, w2P3, b2, out, 1024);
}

// Round 8
// 315.413 us; speedup vs baseline: 1.0008x; 1.0008x over previous
//
#include <hip/hip_runtime.h>
#include <math.h>

#define HIDDEN 1024
#define SEQ    2048
#define NHEAD  16
#define HDIM   64
#define ROWS   (2 * SEQ)

typedef float  floatx4  __attribute__((ext_vector_type(4)));
typedef float  floatx16 __attribute__((ext_vector_type(16)));
typedef __bf16 bf16x8   __attribute__((ext_vector_type(8)));
typedef __bf16 bf16x4   __attribute__((ext_vector_type(4)));

#define AS1(p) ((const __attribute__((address_space(1))) void*)(p))
#define AS3(p) ((__attribute__((address_space(3))) void*)(p))

// swizzled byte-chunk offset (in elements): 16B chunks XOR'd by row&7 (attn)
#define SWZ(row, chunk) ((((chunk) ^ ((row) & 7)) * 8))

// [R7 lesson: XCD-aware block swizzle REGRESSED W1 55.6 vs <44 us — the
// chunked remap forced each XCD to touch all of A (8MB > 4MB L2) and
// thrashed writes (WRITE_SIZE 49 vs 32MB). Default mapping + L3 wins here.
// Do not reintroduce without a per-XCD working-set < 4MB argument.]

// ---------------------------------------------------------------------------
// Prep launch: 6 weight converts + LayerNorm1, one kernel.
// QKV / W1 / W2 -> PLAIN transposed bf16 Bt[n][k] (for the 256-tile core).
// Wo           -> fragment-major BtF (legacy 128-tile core).
// ---------------------------------------------------------------------------
__global__ __launch_bounds__(256) void prep_all(const float* __restrict__ Wq,
                                                const float* __restrict__ Wk,
                                                const float* __restrict__ Wv,
                                                const float* __restrict__ Wo,
                                                const float* __restrict__ W1,
                                                const float* __restrict__ W2,
                                                __bf16* __restrict__ BtQKV,
                                                __bf16* __restrict__ BtO,
                                                __bf16* __restrict__ Bt1,
                                                __bf16* __restrict__ Bt2,
                                                const float* __restrict__ emb,
                                                const float* __restrict__ g1,
                                                const float* __restrict__ be1,
                                                __bf16* __restrict__ h) {
    int id = blockIdx.x;
    int tid = threadIdx.x;
    if (id >= 12288) {
        // ---- LayerNorm1 row ----
        int row = id - 12288;
        size_t i = (size_t)row * HIDDEN + tid * 4;
        float4 v = *(const float4*)(emb + i);
        float s  = v.x + v.y + v.z + v.w;
        float s2 = v.x * v.x + v.y * v.y + v.z * v.z + v.w * v.w;
#pragma unroll
        for (int off = 1; off < 64; off <<= 1) {
            s  += __shfl_xor(s, off, 64);
            s2 += __shfl_xor(s2, off, 64);
        }
        __shared__ float red[8];
        int wid = tid >> 6;
        if ((tid & 63) == 0) { red[wid] = s; red[wid + 4] = s2; }
        __syncthreads();
        s  = red[0] + red[1] + red[2] + red[3];
        s2 = red[4] + red[5] + red[6] + red[7];
        float mu  = s * (1.0f / HIDDEN);
        float var = fmaxf(s2 * (1.0f / HIDDEN) - mu * mu, 0.0f);
        float inv = rsqrtf(var + 1e-5f);
        float4 gv = *(const float4*)(g1 + tid * 4);
        float4 bv = *(const float4*)(be1 + tid * 4);
        bf16x4 o;
        o[0] = (__bf16)((v.x - mu) * inv * gv.x + bv.x);
        o[1] = (__bf16)((v.y - mu) * inv * gv.y + bv.y);
        o[2] = (__bf16)((v.z - mu) * inv * gv.z + bv.z);
        o[3] = (__bf16)((v.w - mu) * inv * gv.w + bv.w);
        *(bf16x4*)(h + i) = o;
        return;
    }
    // ---- weight convert tile (32x32) ----
    __shared__ float t[32][33];
    const float* in; __bf16* out; int K, N, nt, kt;
    if (id < 4096) {
        int job = id >> 10, tt = id & 1023;
        nt = tt & 31; kt = tt >> 5; K = 1024; N = 1024;
        if (job == 0)      { in = Wq; out = BtQKV; }
        else if (job == 1) { in = Wk; out = BtQKV + 1024 * 1024; }
        else if (job == 2) { in = Wv; out = BtQKV + 2 * 1024 * 1024; }
        else               { in = Wo; out = BtO; }
    } else if (id < 8192) {
        int tt = id - 4096;
        nt = tt & 127; kt = tt >> 7; K = 1024; N = 4096; in = W1; out = Bt1;
    } else {
        int tt = id - 8192;
        nt = tt & 31; kt = tt >> 5; K = 4096; N = 1024; in = W2; out = Bt2;
    }
    bool frag = (id >= 3072 && id < 4096);    // only Wo keeps fragment-major
    int n0 = nt * 32, k0 = kt * 32;
    int r  = tid >> 3;             // n within tile
    int c4 = (tid & 7) * 4;        // k run of 4
    float4 v = *(const float4*)(in + (size_t)(k0 + r) * N + n0 + c4);
    t[r][c4 + 0] = v.x; t[r][c4 + 1] = v.y; t[r][c4 + 2] = v.z; t[r][c4 + 3] = v.w;
    __syncthreads();
    bf16x4 o;
    o[0] = (__bf16)t[c4 + 0][r];
    o[1] = (__bf16)t[c4 + 1][r];
    o[2] = (__bf16)t[c4 + 2][r];
    o[3] = (__bf16)t[c4 + 3][r];
    int n = n0 + r, k = k0 + c4;
    if (!frag) {
        *(bf16x4*)(out + (size_t)n * K + k) = o;
    } else {
        size_t blk = (size_t)(n >> 5) * (K >> 4) + (k >> 4);
        int ln = ((k >> 3) & 1) * 32 + (n & 31);
        *(bf16x4*)(out + blk * 512 + ln * 8 + (k & 7)) = o;
    }
}

// ---------------------------------------------------------------------------
// Fused Wo-split-K(x2) reduction + residual + LayerNorm2.
// ---------------------------------------------------------------------------
__global__ __launch_bounds__(256) void red_wo_ln(const float* __restrict__ emb,
                                                 const __bf16* __restrict__ p0,
                                                 const __bf16* __restrict__ p1,
                                                 const float* __restrict__ g,
                                                 const float* __restrict__ beta,
                                                 float* __restrict__ out,
                                                 __bf16* __restrict__ h2) {
    int row = blockIdx.x;
    int tid = threadIdx.x;
    size_t i = (size_t)row * HIDDEN + tid * 4;
    float4 e = *(const float4*)(emb + i);
    bf16x4 a = *(const bf16x4*)(p0 + i);
    bf16x4 b = *(const bf16x4*)(p1 + i);
    float4 v;
    v.x = e.x + (float)a[0] + (float)b[0];
    v.y = e.y + (float)a[1] + (float)b[1];
    v.z = e.z + (float)a[2] + (float)b[2];
    v.w = e.w + (float)a[3] + (float)b[3];
    *(float4*)(out + i) = v;

    float s  = v.x + v.y + v.z + v.w;
    float s2 = v.x * v.x + v.y * v.y + v.z * v.z + v.w * v.w;
#pragma unroll
    for (int off = 1; off < 64; off <<= 1) {
        s  += __shfl_xor(s, off, 64);
        s2 += __shfl_xor(s2, off, 64);
    }
    __shared__ float red[8];
    int wid = tid >> 6;
    if ((tid & 63) == 0) { red[wid] = s; red[wid + 4] = s2; }
    __syncthreads();
    s  = red[0] + red[1] + red[2] + red[3];
    s2 = red[4] + red[5] + red[6] + red[7];
    float mu  = s * (1.0f / HIDDEN);
    float var = fmaxf(s2 * (1.0f / HIDDEN) - mu * mu, 0.0f);
    float inv = rsqrtf(var + 1e-5f);
    float4 gv = *(const float4*)(g + tid * 4);
    float4 bv = *(const float4*)(beta + tid * 4);
    bf16x4 o;
    o[0] = (__bf16)((v.x - mu) * inv * gv.x + bv.x);
    o[1] = (__bf16)((v.y - mu) * inv * gv.y + bv.y);
    o[2] = (__bf16)((v.z - mu) * inv * gv.z + bv.z);
    o[3] = (__bf16)((v.w - mu) * inv * gv.w + bv.w);
    *(bf16x4*)(h2 + i) = o;
}

// ---------------------------------------------------------------------------
// W2 reduction: out += p0+p1+p2+p3 + b2[col]
// ---------------------------------------------------------------------------
__global__ __launch_bounds__(256) void red_w2(const __bf16* __restrict__ p0,
                                              const __bf16* __restrict__ p3,
                                              const float* __restrict__ b2,
                                              float* __restrict__ out,
                                              int N) {
    size_t i = ((size_t)blockIdx.x * 256 + threadIdx.x) * 8;
    const size_t MN = (size_t)ROWS * HIDDEN;
    bf16x8 a = *(const bf16x8*)(p0 + i);
    bf16x8 b = *(const bf16x8*)(p0 + MN + i);
    bf16x8 c = *(const bf16x8*)(p0 + 2 * MN + i);
    bf16x8 d = *(const bf16x8*)(p3 + i);
    int col = (int)(i & (size_t)(N - 1));
    float4 bb0 = *(const float4*)(b2 + col);
    float4 bb1 = *(const float4*)(b2 + col + 4);
    float4 o0 = *(const float4*)(out + i);
    float4 o1 = *(const float4*)(out + i + 4);
    o0.x += (float)a[0] + (float)b[0] + (float)c[0] + (float)d[0] + bb0.x;
    o0.y += (float)a[1] + (float)b[1] + (float)c[1] + (float)d[1] + bb0.y;
    o0.z += (float)a[2] + (float)b[2] + (float)c[2] + (float)d[2] + bb0.z;
    o0.w += (float)a[3] + (float)b[3] + (float)c[3] + (float)d[3] + bb0.w;
    o1.x += (float)a[4] + (float)b[4] + (float)c[4] + (float)d[4] + bb1.x;
    o1.y += (float)a[5] + (float)b[5] + (float)c[5] + (float)d[5] + bb1.y;
    o1.z += (float)a[6] + (float)b[6] + (float)c[6] + (float)d[6] + bb1.z;
    o1.w += (float)a[7] + (float)b[7] + (float)c[7] + (float)d[7] + bb1.w;
    *(float4*)(out + i)     = o0;
    *(float4*)(out + i + 4) = o1;
}

// ---------------------------------------------------------------------------
// Legacy 128x128 MFMA core (Wo split-K only — short-K regime winner).
// ---------------------------------------------------------------------------
__device__ __forceinline__ void mfma_core128(const __bf16* __restrict__ A,
                                             const __bf16* __restrict__ BtF,
                                             int Kstride, int kbase, int Klen,
                                             int m0, int n0, int tid,
                                             floatx16 (&acc)[2][2]) {
    __shared__ __bf16 As[2 * 128 * 32];
    const int BUF = 128 * 32;
    int lane = tid & 63;
    int wave = tid >> 6;
    int wr = wave >> 1, wc = wave & 1;

    int sr = lane >> 2;
    int sk = 8 * ((lane & 3) ^ ((sr >> 1) & 3));
    const __bf16* ga0 = A + (size_t)(m0 + wave * 16 + sr) * Kstride + kbase + sk;
    const __bf16* ga1 = ga0 + (size_t)64 * Kstride;
    __bf16* la0 = &As[wave * 512];
    __bf16* la1 = &As[2048 + wave * 512];

    int fm = lane & 31;
    int gswz = (lane >> 1) & 3;
    int slot0 = ((lane >> 5) + 0) ^ gswz;
    int slot1 = ((lane >> 5) + 2) ^ gswz;

    const __bf16* bb = BtF + ((size_t)((n0 >> 5) + wc * 2) * (Kstride >> 4)) * 512
                     + (size_t)lane * 8;
    const size_t jstr = (size_t)(Kstride >> 4) * 512;
    int ci0 = kbase >> 4;

    __builtin_amdgcn_global_load_lds(AS1(ga0), AS3(la0), 16, 0, 0);
    __builtin_amdgcn_global_load_lds(AS1(ga1), AS3(la1), 16, 0, 0);
    bf16x8 bcur[2][2], bnxt[2][2];
#pragma unroll
    for (int j = 0; j < 2; j++)
#pragma unroll
        for (int t = 0; t < 2; t++)
            bcur[j][t] = *(const bf16x8*)(bb + j * jstr + (size_t)(ci0 + t) * 512);

    int buf = 0;
    for (int k0 = 0; k0 < Klen; k0 += 32, buf ^= 1) {
        __syncthreads();
        if (k0 + 32 < Klen) {
            int nb = (buf ^ 1) * BUF;
            __builtin_amdgcn_global_load_lds(AS1(ga0 + k0 + 32), AS3(la0 + nb), 16, 0, 0);
            __builtin_amdgcn_global_load_lds(AS1(ga1 + k0 + 32), AS3(la1 + nb), 16, 0, 0);
            int ci = ci0 + ((k0 + 32) >> 4);
#pragma unroll
            for (int j = 0; j < 2; j++)
#pragma unroll
                for (int t = 0; t < 2; t++)
                    bnxt[j][t] = *(const bf16x8*)(bb + j * jstr + (size_t)(ci + t) * 512);
        }
        const __bf16* Ab = As + buf * BUF;
        bf16x8 af[2][2];
#pragma unroll
        for (int i = 0; i < 2; i++) {
            const __bf16* rp = Ab + (size_t)(wr * 64 + i * 32 + fm) * 32;
            af[i][0] = *(const bf16x8*)(rp + slot0 * 8);
            af[i][1] = *(const bf16x8*)(rp + slot1 * 8);
        }
#pragma unroll
        for (int t = 0; t < 2; t++)
#pragma unroll
            for (int i = 0; i < 2; i++)
#pragma unroll
                for (int j = 0; j < 2; j++)
                    acc[i][j] = __builtin_amdgcn_mfma_f32_32x32x16_bf16(
                        af[i][t], bcur[j][t], acc[i][j], 0, 0, 0);
#pragma unroll
        for (int j = 0; j < 2; j++)
#pragma unroll
            for (int t = 0; t < 2; t++)
                bcur[j][t] = bnxt[j][t];
    }
}

// ---------------------------------------------------------------------------
// Split-K GEMM on the legacy core (Wo only; z in {0,1}).
// ---------------------------------------------------------------------------
__global__ __launch_bounds__(256) void mgemm_sk(const __bf16* __restrict__ A,
                                                const __bf16* __restrict__ BtF,
                                                __bf16* __restrict__ P0,
                                                __bf16* __restrict__ P3,
                                                int M, int N, int Kstride, int Klen) {
    int z = blockIdx.z;
    __bf16* C = (z == 3) ? P3 : (P0 + (size_t)z * M * N);
    int tid = threadIdx.x;
    int lane = tid & 63;
    int wave = tid >> 6;
    int m0 = blockIdx.x * 128, n0 = blockIdx.y * 128;
    int wr = wave >> 1, wc = wave & 1;
    floatx16 acc[2][2] = {};
    mfma_core128(A, BtF, Kstride, z * Klen, Klen, m0, n0, tid, acc);

#pragma unroll
    for (int i = 0; i < 2; i++) {
#pragma unroll
        for (int j = 0; j < 2; j++) {
            int col  = n0 + wc * 64 + j * 32 + (lane & 31);
            int rowb = m0 + wr * 64 + i * 32 + 4 * (lane >> 5);
#pragma unroll
            for (int reg = 0; reg < 16; reg++) {
                int row = rowb + (reg & 3) + 8 * (reg >> 2);
                C[(size_t)row * N + col] = (__bf16)acc[i][j][reg];
            }
        }
    }
}

// ---------------------------------------------------------------------------
// 256x256 MFMA core, BK=32, 512 threads = 8 waves (2M x 4N), ring-4 LDS,
// counted-vmcnt phase schedule. STG issue moved BEFORE the phase's ds_reads
// (issue-order only; no barrier/ledger change — earlier DMA start).
// ---------------------------------------------------------------------------
template <int KLEN>
__device__ __forceinline__ void mfma_core256(const __bf16* __restrict__ A,
                                             const __bf16* __restrict__ Bt,
                                             int Kstride, int kbase,
                                             int m0, int n0, int tid,
                                             floatx16 (&acc)[4][2]) {
    __shared__ __bf16 lds[8 * 8192];          // 128 KiB
    const int NT = KLEN >> 5;                 // K-tiles of 32 (NT >= 3)
    int l = tid & 63;
    int w = tid >> 6;
    int wr = w >> 2, wc = w & 3;

    int lr  = l >> 2;                                 // row within group
    int lcf = ((l & 3) ^ ((l >> 3) & 3)) * 8;         // pre-swizzled src chunk
    const __bf16* gA0 = A  + (size_t)(m0 + (w * 2 + 0) * 16 + lr) * Kstride + kbase + lcf;
    const __bf16* gA1 = A  + (size_t)(m0 + (w * 2 + 1) * 16 + lr) * Kstride + kbase + lcf;
    const __bf16* gB0 = Bt + (size_t)(n0 + (w * 2 + 0) * 16 + lr) * Kstride + kbase + lcf;
    const __bf16* gB1 = Bt + (size_t)(n0 + (w * 2 + 1) * 16 + lr) * Kstride + kbase + lcf;
    __bf16* lA0 = lds + (w * 2 + 0) * 512;
    __bf16* lA1 = lds + (w * 2 + 1) * 512;
    __bf16* lB0 = lA0 + 32768;
    __bf16* lB1 = lA1 + 32768;

#define STG_A(tt) do { int b_ = (tt) & 3; int ko_ = (tt) * 32;                          \
    __builtin_amdgcn_global_load_lds(AS1(gA0 + ko_), AS3(lA0 + b_ * 8192), 16, 0, 0);   \
    __builtin_amdgcn_global_load_lds(AS1(gA1 + ko_), AS3(lA1 + b_ * 8192), 16, 0, 0); } while (0)
#define STG_B(tt) do { int b_ = (tt) & 3; int ko_ = (tt) * 32;                          \
    __builtin_amdgcn_global_load_lds(AS1(gB0 + ko_), AS3(lB0 + b_ * 8192), 16, 0, 0);   \
    __builtin_amdgcn_global_load_lds(AS1(gB1 + ko_), AS3(lB1 + b_ * 8192), 16, 0, 0); } while (0)

    STG_A(0); STG_B(0);
    STG_A(1); STG_B(1);
    STG_A(2); STG_B(2);

    int fm = l & 31, cc = l >> 5;
    int sw = (fm >> 1) & 3;
    int pc0 = ((0 + cc) ^ sw) * 8;
    int pc1 = ((2 + cc) ^ sw) * 8;
    int aB  = (wr * 128 + fm) * 32;
    int bB  = (wc * 64 + fm) * 32 + 32768;

    for (int t = 0; t < NT; ++t) {
        if (t + 3 <= NT)
            asm volatile("s_waitcnt vmcnt(8)\n\ts_barrier" ::: "memory");
        else if (t + 2 <= NT)
            asm volatile("s_waitcnt vmcnt(4)\n\ts_barrier" ::: "memory");
        else
            asm volatile("s_waitcnt vmcnt(0)\n\ts_barrier" ::: "memory");

        const __bf16* base = lds + (t & 3) * 8192;

        // ---- phase 0: issue STG_A(t+3) first (no dep on reads), then reads
        if (t + 3 < NT) STG_A(t + 3);
        bf16x8 a0[2][2], bfr[2][2];
        a0[0][0]  = *(const bf16x8*)(base + aB + 0 * 1024 + pc0);
        a0[0][1]  = *(const bf16x8*)(base + aB + 0 * 1024 + pc1);
        a0[1][0]  = *(const bf16x8*)(base + aB + 1 * 1024 + pc0);
        a0[1][1]  = *(const bf16x8*)(base + aB + 1 * 1024 + pc1);
        bfr[0][0] = *(const bf16x8*)(base + bB + 0 * 1024 + pc0);
        bfr[0][1] = *(const bf16x8*)(base + bB + 0 * 1024 + pc1);
        bfr[1][0] = *(const bf16x8*)(base + bB + 1 * 1024 + pc0);
        bfr[1][1] = *(const bf16x8*)(base + bB + 1 * 1024 + pc1);
        __builtin_amdgcn_s_barrier();
        asm volatile("s_waitcnt lgkmcnt(0)" ::: "memory");
        __builtin_amdgcn_sched_barrier(0);
        __builtin_amdgcn_s_setprio(1);
#pragma unroll
        for (int u = 0; u < 2; ++u)
#pragma unroll
            for (int i = 0; i < 2; ++i)
#pragma unroll
                for (int j = 0; j < 2; ++j)
                    acc[i][j] = __builtin_amdgcn_mfma_f32_32x32x16_bf16(
                        a0[i][u], bfr[j][u], acc[i][j], 0, 0, 0);
        __builtin_amdgcn_s_setprio(0);

        // ---- phase 1: issue STG_B(t+3) first, then reads
        if (t + 3 < NT) STG_B(t + 3);
        bf16x8 a1[2][2];
        a1[0][0] = *(const bf16x8*)(base + aB + 2 * 1024 + pc0);
        a1[0][1] = *(const bf16x8*)(base + aB + 2 * 1024 + pc1);
        a1[1][0] = *(const bf16x8*)(base + aB + 3 * 1024 + pc0);
        a1[1][1] = *(const bf16x8*)(base + aB + 3 * 1024 + pc1);
        __builtin_amdgcn_s_barrier();
        asm volatile("s_waitcnt lgkmcnt(0)" ::: "memory");
        __builtin_amdgcn_sched_barrier(0);
        __builtin_amdgcn_s_setprio(1);
#pragma unroll
        for (int u = 0; u < 2; ++u)
#pragma unroll
            for (int i = 0; i < 2; ++i)
#pragma unroll
                for (int j = 0; j < 2; ++j)
                    acc[2 + i][j] = __builtin_amdgcn_mfma_f32_32x32x16_bf16(
                        a1[i][u], bfr[j][u], acc[2 + i][j], 0, 0, 0);
        __builtin_amdgcn_s_setprio(0);
    }
#undef STG_A
#undef STG_B
}

// ---------------------------------------------------------------------------
// 256-tile GEMM with bias/ReLU epilogue (W1). Grid: (M/256, N/256), 512 thr.
// ---------------------------------------------------------------------------
template <bool BIAS, bool RELU>
__global__ __launch_bounds__(512, 2) void mgemm256(const __bf16* __restrict__ A,
                                                   const __bf16* __restrict__ Bt,
                                                   const float* __restrict__ bias,
                                                   __bf16* __restrict__ C,
                                                   int N, int Kstride) {
    int tid = threadIdx.x;
    int l = tid & 63, w = tid >> 6;
    int wr = w >> 2, wc = w & 3;
    int m0 = blockIdx.x * 256, n0 = blockIdx.y * 256;
    floatx16 acc[4][2] = {};
    mfma_core256<1024>(A, Bt, Kstride, 0, m0, n0, tid, acc);
#pragma unroll
    for (int i = 0; i < 4; ++i)
#pragma unroll
        for (int j = 0; j < 2; ++j) {
            int col  = n0 + wc * 64 + j * 32 + (l & 31);
            int rowb = m0 + wr * 128 + i * 32 + 4 * (l >> 5);
            float bv = 0.0f;
            if (BIAS) bv = bias[col];
#pragma unroll
            for (int reg = 0; reg < 16; ++reg) {
                int row = rowb + (reg & 3) + 8 * (reg >> 2);
                float v = acc[i][j][reg] + bv;
                if (RELU) v = fmaxf(v, 0.0f);
                C[(size_t)row * N + col] = (__bf16)v;
            }
        }
}

// ---------------------------------------------------------------------------
// 256-tile split-K GEMM (W2, KLEN=1024): z picks K chunk; bf16 partials.
// ---------------------------------------------------------------------------
template <int KLEN>
__global__ __launch_bounds__(512, 2) void mgemm256_sk(const __bf16* __restrict__ A,
                                                      const __bf16* __restrict__ Bt,
                                                      __bf16* __restrict__ P0,
                                                      __bf16* __restrict__ P3,
                                                      int M, int N, int Kstride) {
    int z = blockIdx.z;
    __bf16* C = (z == 3) ? P3 : (P0 + (size_t)z * M * N);
    int tid = threadIdx.x;
    int l = tid & 63, w = tid >> 6;
    int wr = w >> 2, wc = w & 3;
    int m0 = blockIdx.x * 256, n0 = blockIdx.y * 256;
    floatx16 acc[4][2] = {};
    mfma_core256<KLEN>(A, Bt, Kstride, z * KLEN, m0, n0, tid, acc);
#pragma unroll
    for (int i = 0; i < 4; ++i)
#pragma unroll
        for (int j = 0; j < 2; ++j) {
            int col  = n0 + wc * 64 + j * 32 + (l & 31);
            int rowb = m0 + wr * 128 + i * 32 + 4 * (l >> 5);
#pragma unroll
            for (int reg = 0; reg < 16; ++reg) {
                int row = rowb + (reg & 3) + 8 * (reg >> 2);
                C[(size_t)row * N + col] = (__bf16)acc[i][j][reg];
            }
        }
}

// ---------------------------------------------------------------------------
// 256-tile QKV GEMM: q,k columns to qkv[4096][3072]; v columns written only
// as transposed Vt[bh][d][T]. Grid: (16, 12), 512 thr.
// ---------------------------------------------------------------------------
__global__ __launch_bounds__(512, 2) void mgemm256_qkv(const __bf16* __restrict__ A,
                                                       const __bf16* __restrict__ Bt,
                                                       __bf16* __restrict__ C,
                                                       __bf16* __restrict__ Vt) {
    const int N = 3072;
    int tid = threadIdx.x;
    int l = tid & 63, w = tid >> 6;
    int wr = w >> 2, wc = w & 3;
    int m0 = blockIdx.x * 256, n0 = blockIdx.y * 256;
    floatx16 acc[4][2] = {};
    mfma_core256<1024>(A, Bt, 1024, 0, m0, n0, tid, acc);
#pragma unroll
    for (int i = 0; i < 4; ++i)
#pragma unroll
        for (int j = 0; j < 2; ++j) {
            int col  = n0 + wc * 64 + j * 32 + (l & 31);
            int rowb = m0 + wr * 128 + i * 32 + 4 * (l >> 5);
            if (col < 2048) {
#pragma unroll
                for (int reg = 0; reg < 16; ++reg) {
                    int row = rowb + (reg & 3) + 8 * (reg >> 2);
                    C[(size_t)row * N + col] = (__bf16)acc[i][j][reg];
                }
            } else {
                int vcol = col - 2048;
                int hh = vcol >> 6, dd = vcol & 63;
#pragma unroll
                for (int rq = 0; rq < 4; rq++) {
                    int row0 = rowb + 8 * rq;
                    int bb = row0 >> 11;
                    int tt = row0 & 2047;
                    bf16x4 pack;
                    pack[0] = (__bf16)acc[i][j][4 * rq + 0];
                    pack[1] = (__bf16)acc[i][j][4 * rq + 1];
                    pack[2] = (__bf16)acc[i][j][4 * rq + 2];
                    pack[3] = (__bf16)acc[i][j][4 * rq + 3];
                    *(bf16x4*)&Vt[(((size_t)bb * 16 + hh) * 64 + dd) * SEQ + tt] = pack;
                }
            }
        }
}

// ---------------------------------------------------------------------------
// MFMA flash attention (verified R5 config, 43.8 us): single-buffered K/V,
// no-max exp2 softmax, ones-MFMA l, K/V register prefetch, setprio.
// [dbuf variant measured slower: 47.7 us R6 — do not reintroduce]
// ---------------------------------------------------------------------------
__global__ __launch_bounds__(256) void attn_mfma(const __bf16* __restrict__ qkv,
                                                 const __bf16* __restrict__ Vt,
                                                 __bf16* __restrict__ ctx) {
    __shared__ __bf16 Ks[64 * 64];
    __shared__ __bf16 Vs[64 * 64];
    __shared__ __bf16 Ps[4][16 * 64];
    const int QKVW = 3 * HIDDEN;

    int bh = blockIdx.x;
    int qt = gridDim.y - 1 - blockIdx.y;
    int b = bh >> 4, h = bh & 15;
    int tid = threadIdx.x;
    int lane = tid & 63;
    int w = tid >> 6;
    int m = lane & 15;
    int g = lane >> 4;

    const float QSC = 1.44269504f / 8.0f;
    bf16x8 qf[2];
    {
        const __bf16* Qp = qkv + (size_t)(b * SEQ + qt * 64 + w * 16 + m) * QKVW
                         + h * HDIM + g * 8;
        qf[0] = *(const bf16x8*)(Qp);
        qf[1] = *(const bf16x8*)(Qp + 32);
#pragma unroll
        for (int t = 0; t < 2; t++)
#pragma unroll
            for (int i = 0; i < 8; i++)
                qf[t][i] = (__bf16)((float)qf[t][i] * QSC);
    }

    bf16x8 onesf;
#pragma unroll
    for (int i = 0; i < 8; i++) onesf[i] = (__bf16)1.0f;

    floatx4 oacc[4] = {};
    floatx4 lacc = {};

    int srow = tid >> 2;
    int sc0  = (tid & 3) * 2;
    const __bf16* Kg = qkv + (size_t)(b * SEQ) * QKVW + HIDDEN + h * HDIM;
    const __bf16* Vg = Vt + (size_t)bh * HDIM * SEQ;

    bf16x8 pk0, pk1, pv0, pv1;
    {
        const __bf16* kp = Kg + (size_t)srow * QKVW + sc0 * 8;
        pk0 = *(const bf16x8*)kp;
        pk1 = *(const bf16x8*)(kp + 8);
        const __bf16* vp = Vg + (size_t)srow * SEQ + sc0 * 8;
        pv0 = *(const bf16x8*)vp;
        pv1 = *(const bf16x8*)(vp + 8);
    }

    for (int kt = 0; kt <= qt; kt++) {
        __syncthreads();
        *(bf16x8*)&Ks[srow * 64 + SWZ(srow, sc0)]     = pk0;
        *(bf16x8*)&Ks[srow * 64 + SWZ(srow, sc0 + 1)] = pk1;
        *(bf16x8*)&Vs[srow * 64 + SWZ(srow, sc0)]     = pv0;
        *(bf16x8*)&Vs[srow * 64 + SWZ(srow, sc0 + 1)] = pv1;
        __syncthreads();

        if (kt < qt) {
            const __bf16* kp = Kg + (size_t)((kt + 1) * 64 + srow) * QKVW + sc0 * 8;
            pk0 = *(const bf16x8*)kp;
            pk1 = *(const bf16x8*)(kp + 8);
            const __bf16* vp = Vg + (size_t)srow * SEQ + (kt + 1) * 64 + sc0 * 8;
            pv0 = *(const bf16x8*)vp;
            pv1 = *(const bf16x8*)(vp + 8);
        }

        floatx4 sacc[4] = {};
        __builtin_amdgcn_s_setprio(1);
#pragma unroll
        for (int j = 0; j < 4; j++) {
#pragma unroll
            for (int t = 0; t < 2; t++) {
                int kr = 16 * j + m;
                bf16x8 kf = *(const bf16x8*)&Ks[kr * 64 + SWZ(kr, g + 4 * t)];
                sacc[j] = __builtin_amdgcn_mfma_f32_16x16x32_bf16(
                    qf[t], kf, sacc[j], 0, 0, 0);
            }
        }
        __builtin_amdgcn_s_setprio(0);

        if (kt == qt) {
            int qlocal = w * 16 + 4 * g;
#pragma unroll
            for (int j = 0; j < 4; j++)
#pragma unroll
                for (int r = 0; r < 4; r++)
                    if (16 * j + m > qlocal + r) sacc[j][r] = -INFINITY;
        }

        __bf16* Pw = &Ps[w][0];
#pragma unroll
        for (int j = 0; j < 4; j++)
#pragma unroll
            for (int r = 0; r < 4; r++) {
                float p = exp2f(sacc[j][r]);
                int row = 4 * g + r;
                int key = 16 * j + m;
                Pw[row * 64 + SWZ(row, key >> 3) + (key & 7)] = (__bf16)p;
            }

        __builtin_amdgcn_s_setprio(1);
#pragma unroll
        for (int t = 0; t < 2; t++) {
            bf16x8 pf = *(const bf16x8*)&Pw[m * 64 + SWZ(m, g + 4 * t)];
            lacc = __builtin_amdgcn_mfma_f32_16x16x32_bf16(pf, onesf, lacc, 0, 0, 0);
#pragma unroll
            for (int jd = 0; jd < 4; jd++) {
                int vr = 16 * jd + m;
                bf16x8 vf = *(const bf16x8*)&Vs[vr * 64 + SWZ(vr, g + 4 * t)];
                oacc[jd] = __builtin_amdgcn_mfma_f32_16x16x32_bf16(
                    pf, vf, oacc[jd], 0, 0, 0);
            }
        }
        __builtin_amdgcn_s_setprio(0);
    }

#pragma unroll
    for (int r = 0; r < 4; r++) {
        float invl = 1.0f / lacc[r];
        int row = qt * 64 + w * 16 + 4 * g + r;
        __bf16* cp = ctx + (size_t)(b * SEQ + row) * HIDDEN + h * HDIM;
#pragma unroll
        for (int jd = 0; jd < 4; jd++)
            cp[16 * jd + m] = (__bf16)(oacc[jd][r] * invl);
    }
}

// ---------------------------------------------------------------------------
extern "C" void kernel_launch(void* const* d_in, const int* in_sizes, int n_in,
                              void* d_out, int out_size, void* d_ws, size_t ws_size,
                              hipStream_t stream) {
    (void)in_sizes; (void)n_in; (void)out_size; (void)ws_size;
    const float* emb = (const float*)d_in[0];
    const float* Wq  = (const float*)d_in[1];
    const float* Wk  = (const float*)d_in[2];
    const float* Wv  = (const float*)d_in[3];
    const float* Wo  = (const float*)d_in[4];
    const float* W1  = (const float*)d_in[5];
    const float* b1  = (const float*)d_in[6];
    const float* W2  = (const float*)d_in[7];
    const float* b2  = (const float*)d_in[8];
    const float* g1  = (const float*)d_in[9];
    const float* be1 = (const float*)d_in[10];
    const float* g2  = (const float*)d_in[11];
    const float* be2 = (const float*)d_in[12];
    float* out = (float*)d_out;

    // ws layout (bf16 elems; ME = 1M elems = 2MB). Total 36 ME = 72 MB.
    //   [0,4)   h (LN1) -> ctx (attn out) -> ff1 head
    //   [4,16)  qkv (q,k cols used) -> Wo partials [4,12) -> ff1
    //   [16,20) h2 -> W2 partial z0
    //   [20,24) BtQKV+BtO -> W2 partial z1
    //   [24,28) Bt1 -> W2 partial z2
    //   [28,32) Bt2 (alive through W2 gemm)
    //   [32,36) Vt -> W2 partial z3
    __bf16* wsb = (__bf16*)d_ws;
    const size_t ME = 1024 * 1024;
    __bf16* h     = wsb;
    __bf16* qkv   = wsb + 4 * ME;
    __bf16* ctx   = wsb;
    __bf16* ff1   = wsb;
    __bf16* h2    = wsb + 16 * ME;
    __bf16* BtQKV = wsb + 20 * ME;
    __bf16* BtO   = wsb + 23 * ME;
    __bf16* Bt1   = wsb + 24 * ME;
    __bf16* Bt2   = wsb + 28 * ME;
    __bf16* Vt    = wsb + 32 * ME;
    __bf16* woP   = wsb + 4 * ME;    // 2 x 4 ME
    __bf16* w2P0  = wsb + 16 * ME;   // z0..z2 contiguous (12 ME)
    __bf16* w2P3  = wsb + 32 * ME;   // z3

    prep_all<<<16384, 256, 0, stream>>>(Wq, Wk, Wv, Wo, W1, W2,
                                        BtQKV, BtO, Bt1, Bt2,
                                        emb, g1, be1, h);

    mgemm256_qkv<<<dim3(16, 12), 512, 0, stream>>>(h, BtQKV, qkv, Vt);

    attn_mfma<<<dim3(32, 32), 256, 0, stream>>>(qkv, Vt, ctx);

    // Wo split-K x2 on the legacy 128-tile core, bf16 partials
    mgemm_sk<<<dim3(32, 8, 2), 256, 0, stream>>>(
        ctx, BtO, woP, nullptr, ROWS, 1024, 1024, 512);
    red_wo_ln<<<ROWS, 256, 0, stream>>>(emb, woP, woP + 4 * ME, g2, be2, out, h2);

    mgemm256<true, true><<<dim3(16, 16), 512, 0, stream>>>(
        h2, Bt1, b1, ff1, 4096, 1024);

    // W2 split-K x4 on the 256-tile core, bf16 partials
    mgemm256_sk<1024><<<dim3(16, 4, 4), 512, 0, stream>>>(
        ff1, Bt2, w2P0, w2P3, ROWS, 1024, 4096);
    red_w2<<<2048, 256, 0, stream>>>(w2P0, w2P3, b2, out, 1024);
}

// Round 9
// 312.770 us; speedup vs baseline: 1.0092x; 1.0085x over previous
//
#include <hip/hip_runtime.h>
#include <math.h>

#define HIDDEN 1024
#define SEQ    2048
#define NHEAD  16
#define HDIM   64
#define ROWS   (2 * SEQ)

typedef float  floatx4  __attribute__((ext_vector_type(4)));
typedef float  floatx16 __attribute__((ext_vector_type(16)));
typedef __bf16 bf16x8   __attribute__((ext_vector_type(8)));
typedef __bf16 bf16x4   __attribute__((ext_vector_type(4)));

#define AS1(p) ((const __attribute__((address_space(1))) void*)(p))
#define AS3(p) ((__attribute__((address_space(3))) void*)(p))

// swizzled byte-chunk offset (in elements): 16B chunks XOR'd by row&7 (attn)
#define SWZ(row, chunk) ((((chunk) ^ ((row) & 7)) * 8))

// [R7 lesson: XCD block swizzle regressed W1 (per-XCD A-working-set 8MB > 4MB
//  L2 → thrash). R8 lesson: issuing STG before the phase ds_reads regressed
//  ~15us total (VMEM issue on the ds_read->barrier->MFMA critical path).
//  Keep the R2-verified ordering: ds_reads, then STG, then barrier.]

// ---------------------------------------------------------------------------
// Prep launch: 6 weight converts + LayerNorm1, one kernel.
// QKV / W1 / W2 -> PLAIN transposed bf16 Bt[n][k] (for the 256-tile core).
// Wo           -> fragment-major BtF (legacy 128-tile core).
// ---------------------------------------------------------------------------
__global__ __launch_bounds__(256) void prep_all(const float* __restrict__ Wq,
                                                const float* __restrict__ Wk,
                                                const float* __restrict__ Wv,
                                                const float* __restrict__ Wo,
                                                const float* __restrict__ W1,
                                                const float* __restrict__ W2,
                                                __bf16* __restrict__ BtQKV,
                                                __bf16* __restrict__ BtO,
                                                __bf16* __restrict__ Bt1,
                                                __bf16* __restrict__ Bt2,
                                                const float* __restrict__ emb,
                                                const float* __restrict__ g1,
                                                const float* __restrict__ be1,
                                                __bf16* __restrict__ h) {
    int id = blockIdx.x;
    int tid = threadIdx.x;
    if (id >= 12288) {
        // ---- LayerNorm1 row ----
        int row = id - 12288;
        size_t i = (size_t)row * HIDDEN + tid * 4;
        float4 v = *(const float4*)(emb + i);
        float s  = v.x + v.y + v.z + v.w;
        float s2 = v.x * v.x + v.y * v.y + v.z * v.z + v.w * v.w;
#pragma unroll
        for (int off = 1; off < 64; off <<= 1) {
            s  += __shfl_xor(s, off, 64);
            s2 += __shfl_xor(s2, off, 64);
        }
        __shared__ float red[8];
        int wid = tid >> 6;
        if ((tid & 63) == 0) { red[wid] = s; red[wid + 4] = s2; }
        __syncthreads();
        s  = red[0] + red[1] + red[2] + red[3];
        s2 = red[4] + red[5] + red[6] + red[7];
        float mu  = s * (1.0f / HIDDEN);
        float var = fmaxf(s2 * (1.0f / HIDDEN) - mu * mu, 0.0f);
        float inv = rsqrtf(var + 1e-5f);
        float4 gv = *(const float4*)(g1 + tid * 4);
        float4 bv = *(const float4*)(be1 + tid * 4);
        bf16x4 o;
        o[0] = (__bf16)((v.x - mu) * inv * gv.x + bv.x);
        o[1] = (__bf16)((v.y - mu) * inv * gv.y + bv.y);
        o[2] = (__bf16)((v.z - mu) * inv * gv.z + bv.z);
        o[3] = (__bf16)((v.w - mu) * inv * gv.w + bv.w);
        *(bf16x4*)(h + i) = o;
        return;
    }
    // ---- weight convert tile (32x32) ----
    __shared__ float t[32][33];
    const float* in; __bf16* out; int K, N, nt, kt;
    if (id < 4096) {
        int job = id >> 10, tt = id & 1023;
        nt = tt & 31; kt = tt >> 5; K = 1024; N = 1024;
        if (job == 0)      { in = Wq; out = BtQKV; }
        else if (job == 1) { in = Wk; out = BtQKV + 1024 * 1024; }
        else if (job == 2) { in = Wv; out = BtQKV + 2 * 1024 * 1024; }
        else               { in = Wo; out = BtO; }
    } else if (id < 8192) {
        int tt = id - 4096;
        nt = tt & 127; kt = tt >> 7; K = 1024; N = 4096; in = W1; out = Bt1;
    } else {
        int tt = id - 8192;
        nt = tt & 31; kt = tt >> 5; K = 4096; N = 1024; in = W2; out = Bt2;
    }
    bool frag = (id >= 3072 && id < 4096);    // only Wo keeps fragment-major
    int n0 = nt * 32, k0 = kt * 32;
    int r  = tid >> 3;             // n within tile
    int c4 = (tid & 7) * 4;        // k run of 4
    float4 v = *(const float4*)(in + (size_t)(k0 + r) * N + n0 + c4);
    t[r][c4 + 0] = v.x; t[r][c4 + 1] = v.y; t[r][c4 + 2] = v.z; t[r][c4 + 3] = v.w;
    __syncthreads();
    bf16x4 o;
    o[0] = (__bf16)t[c4 + 0][r];
    o[1] = (__bf16)t[c4 + 1][r];
    o[2] = (__bf16)t[c4 + 2][r];
    o[3] = (__bf16)t[c4 + 3][r];
    int n = n0 + r, k = k0 + c4;
    if (!frag) {
        *(bf16x4*)(out + (size_t)n * K + k) = o;
    } else {
        size_t blk = (size_t)(n >> 5) * (K >> 4) + (k >> 4);
        int ln = ((k >> 3) & 1) * 32 + (n & 31);
        *(bf16x4*)(out + blk * 512 + ln * 8 + (k & 7)) = o;
    }
}

// ---------------------------------------------------------------------------
// Fused Wo-split-K(x2) reduction + residual + LayerNorm2.
// ---------------------------------------------------------------------------
__global__ __launch_bounds__(256) void red_wo_ln(const float* __restrict__ emb,
                                                 const __bf16* __restrict__ p0,
                                                 const __bf16* __restrict__ p1,
                                                 const float* __restrict__ g,
                                                 const float* __restrict__ beta,
                                                 float* __restrict__ out,
                                                 __bf16* __restrict__ h2) {
    int row = blockIdx.x;
    int tid = threadIdx.x;
    size_t i = (size_t)row * HIDDEN + tid * 4;
    float4 e = *(const float4*)(emb + i);
    bf16x4 a = *(const bf16x4*)(p0 + i);
    bf16x4 b = *(const bf16x4*)(p1 + i);
    float4 v;
    v.x = e.x + (float)a[0] + (float)b[0];
    v.y = e.y + (float)a[1] + (float)b[1];
    v.z = e.z + (float)a[2] + (float)b[2];
    v.w = e.w + (float)a[3] + (float)b[3];
    *(float4*)(out + i) = v;

    float s  = v.x + v.y + v.z + v.w;
    float s2 = v.x * v.x + v.y * v.y + v.z * v.z + v.w * v.w;
#pragma unroll
    for (int off = 1; off < 64; off <<= 1) {
        s  += __shfl_xor(s, off, 64);
        s2 += __shfl_xor(s2, off, 64);
    }
    __shared__ float red[8];
    int wid = tid >> 6;
    if ((tid & 63) == 0) { red[wid] = s; red[wid + 4] = s2; }
    __syncthreads();
    s  = red[0] + red[1] + red[2] + red[3];
    s2 = red[4] + red[5] + red[6] + red[7];
    float mu  = s * (1.0f / HIDDEN);
    float var = fmaxf(s2 * (1.0f / HIDDEN) - mu * mu, 0.0f);
    float inv = rsqrtf(var + 1e-5f);
    float4 gv = *(const float4*)(g + tid * 4);
    float4 bv = *(const float4*)(beta + tid * 4);
    bf16x4 o;
    o[0] = (__bf16)((v.x - mu) * inv * gv.x + bv.x);
    o[1] = (__bf16)((v.y - mu) * inv * gv.y + bv.y);
    o[2] = (__bf16)((v.z - mu) * inv * gv.z + bv.z);
    o[3] = (__bf16)((v.w - mu) * inv * gv.w + bv.w);
    *(bf16x4*)(h2 + i) = o;
}

// ---------------------------------------------------------------------------
// W2 reduction: out += p0+p1+p2+p3 + b2[col]
// ---------------------------------------------------------------------------
__global__ __launch_bounds__(256) void red_w2(const __bf16* __restrict__ p0,
                                              const __bf16* __restrict__ p3,
                                              const float* __restrict__ b2,
                                              float* __restrict__ out,
                                              int N) {
    size_t i = ((size_t)blockIdx.x * 256 + threadIdx.x) * 8;
    const size_t MN = (size_t)ROWS * HIDDEN;
    bf16x8 a = *(const bf16x8*)(p0 + i);
    bf16x8 b = *(const bf16x8*)(p0 + MN + i);
    bf16x8 c = *(const bf16x8*)(p0 + 2 * MN + i);
    bf16x8 d = *(const bf16x8*)(p3 + i);
    int col = (int)(i & (size_t)(N - 1));
    float4 bb0 = *(const float4*)(b2 + col);
    float4 bb1 = *(const float4*)(b2 + col + 4);
    float4 o0 = *(const float4*)(out + i);
    float4 o1 = *(const float4*)(out + i + 4);
    o0.x += (float)a[0] + (float)b[0] + (float)c[0] + (float)d[0] + bb0.x;
    o0.y += (float)a[1] + (float)b[1] + (float)c[1] + (float)d[1] + bb0.y;
    o0.z += (float)a[2] + (float)b[2] + (float)c[2] + (float)d[2] + bb0.z;
    o0.w += (float)a[3] + (float)b[3] + (float)c[3] + (float)d[3] + bb0.w;
    o1.x += (float)a[4] + (float)b[4] + (float)c[4] + (float)d[4] + bb1.x;
    o1.y += (float)a[5] + (float)b[5] + (float)c[5] + (float)d[5] + bb1.y;
    o1.z += (float)a[6] + (float)b[6] + (float)c[6] + (float)d[6] + bb1.z;
    o1.w += (float)a[7] + (float)b[7] + (float)c[7] + (float)d[7] + bb1.w;
    *(float4*)(out + i)     = o0;
    *(float4*)(out + i + 4) = o1;
}

// ---------------------------------------------------------------------------
// Legacy 128x128 MFMA core (Wo split-K only — short-K regime winner).
// ---------------------------------------------------------------------------
__device__ __forceinline__ void mfma_core128(const __bf16* __restrict__ A,
                                             const __bf16* __restrict__ BtF,
                                             int Kstride, int kbase, int Klen,
                                             int m0, int n0, int tid,
                                             floatx16 (&acc)[2][2]) {
    __shared__ __bf16 As[2 * 128 * 32];
    const int BUF = 128 * 32;
    int lane = tid & 63;
    int wave = tid >> 6;
    int wr = wave >> 1, wc = wave & 1;

    int sr = lane >> 2;
    int sk = 8 * ((lane & 3) ^ ((sr >> 1) & 3));
    const __bf16* ga0 = A + (size_t)(m0 + wave * 16 + sr) * Kstride + kbase + sk;
    const __bf16* ga1 = ga0 + (size_t)64 * Kstride;
    __bf16* la0 = &As[wave * 512];
    __bf16* la1 = &As[2048 + wave * 512];

    int fm = lane & 31;
    int gswz = (lane >> 1) & 3;
    int slot0 = ((lane >> 5) + 0) ^ gswz;
    int slot1 = ((lane >> 5) + 2) ^ gswz;

    const __bf16* bb = BtF + ((size_t)((n0 >> 5) + wc * 2) * (Kstride >> 4)) * 512
                     + (size_t)lane * 8;
    const size_t jstr = (size_t)(Kstride >> 4) * 512;
    int ci0 = kbase >> 4;

    __builtin_amdgcn_global_load_lds(AS1(ga0), AS3(la0), 16, 0, 0);
    __builtin_amdgcn_global_load_lds(AS1(ga1), AS3(la1), 16, 0, 0);
    bf16x8 bcur[2][2], bnxt[2][2];
#pragma unroll
    for (int j = 0; j < 2; j++)
#pragma unroll
        for (int t = 0; t < 2; t++)
            bcur[j][t] = *(const bf16x8*)(bb + j * jstr + (size_t)(ci0 + t) * 512);

    int buf = 0;
    for (int k0 = 0; k0 < Klen; k0 += 32, buf ^= 1) {
        __syncthreads();
        if (k0 + 32 < Klen) {
            int nb = (buf ^ 1) * BUF;
            __builtin_amdgcn_global_load_lds(AS1(ga0 + k0 + 32), AS3(la0 + nb), 16, 0, 0);
            __builtin_amdgcn_global_load_lds(AS1(ga1 + k0 + 32), AS3(la1 + nb), 16, 0, 0);
            int ci = ci0 + ((k0 + 32) >> 4);
#pragma unroll
            for (int j = 0; j < 2; j++)
#pragma unroll
                for (int t = 0; t < 2; t++)
                    bnxt[j][t] = *(const bf16x8*)(bb + j * jstr + (size_t)(ci + t) * 512);
        }
        const __bf16* Ab = As + buf * BUF;
        bf16x8 af[2][2];
#pragma unroll
        for (int i = 0; i < 2; i++) {
            const __bf16* rp = Ab + (size_t)(wr * 64 + i * 32 + fm) * 32;
            af[i][0] = *(const bf16x8*)(rp + slot0 * 8);
            af[i][1] = *(const bf16x8*)(rp + slot1 * 8);
        }
#pragma unroll
        for (int t = 0; t < 2; t++)
#pragma unroll
            for (int i = 0; i < 2; i++)
#pragma unroll
                for (int j = 0; j < 2; j++)
                    acc[i][j] = __builtin_amdgcn_mfma_f32_32x32x16_bf16(
                        af[i][t], bcur[j][t], acc[i][j], 0, 0, 0);
#pragma unroll
        for (int j = 0; j < 2; j++)
#pragma unroll
            for (int t = 0; t < 2; t++)
                bcur[j][t] = bnxt[j][t];
    }
}

// ---------------------------------------------------------------------------
// Split-K GEMM on the legacy core (Wo only; z in {0,1}).
// ---------------------------------------------------------------------------
__global__ __launch_bounds__(256) void mgemm_sk(const __bf16* __restrict__ A,
                                                const __bf16* __restrict__ BtF,
                                                __bf16* __restrict__ P0,
                                                __bf16* __restrict__ P3,
                                                int M, int N, int Kstride, int Klen) {
    int z = blockIdx.z;
    __bf16* C = (z == 3) ? P3 : (P0 + (size_t)z * M * N);
    int tid = threadIdx.x;
    int lane = tid & 63;
    int wave = tid >> 6;
    int m0 = blockIdx.x * 128, n0 = blockIdx.y * 128;
    int wr = wave >> 1, wc = wave & 1;
    floatx16 acc[2][2] = {};
    mfma_core128(A, BtF, Kstride, z * Klen, Klen, m0, n0, tid, acc);

#pragma unroll
    for (int i = 0; i < 2; i++) {
#pragma unroll
        for (int j = 0; j < 2; j++) {
            int col  = n0 + wc * 64 + j * 32 + (lane & 31);
            int rowb = m0 + wr * 64 + i * 32 + 4 * (lane >> 5);
#pragma unroll
            for (int reg = 0; reg < 16; reg++) {
                int row = rowb + (reg & 3) + 8 * (reg >> 2);
                C[(size_t)row * N + col] = (__bf16)acc[i][j][reg];
            }
        }
    }
}

// ---------------------------------------------------------------------------
// 256x256 MFMA core, BK=32, 512 threads = 8 waves (2M x 4N), ring-4 LDS,
// counted-vmcnt phase schedule. R2-verified ordering: ds_reads first, STG
// between reads and barrier. (STG-early variant measured −15us total, R8.)
// ---------------------------------------------------------------------------
template <int KLEN>
__device__ __forceinline__ void mfma_core256(const __bf16* __restrict__ A,
                                             const __bf16* __restrict__ Bt,
                                             int Kstride, int kbase,
                                             int m0, int n0, int tid,
                                             floatx16 (&acc)[4][2]) {
    __shared__ __bf16 lds[8 * 8192];          // 128 KiB
    const int NT = KLEN >> 5;                 // K-tiles of 32 (NT >= 3)
    int l = tid & 63;
    int w = tid >> 6;
    int wr = w >> 2, wc = w & 3;

    int lr  = l >> 2;                                 // row within group
    int lcf = ((l & 3) ^ ((l >> 3) & 3)) * 8;         // pre-swizzled src chunk
    const __bf16* gA0 = A  + (size_t)(m0 + (w * 2 + 0) * 16 + lr) * Kstride + kbase + lcf;
    const __bf16* gA1 = A  + (size_t)(m0 + (w * 2 + 1) * 16 + lr) * Kstride + kbase + lcf;
    const __bf16* gB0 = Bt + (size_t)(n0 + (w * 2 + 0) * 16 + lr) * Kstride + kbase + lcf;
    const __bf16* gB1 = Bt + (size_t)(n0 + (w * 2 + 1) * 16 + lr) * Kstride + kbase + lcf;
    __bf16* lA0 = lds + (w * 2 + 0) * 512;
    __bf16* lA1 = lds + (w * 2 + 1) * 512;
    __bf16* lB0 = lA0 + 32768;
    __bf16* lB1 = lA1 + 32768;

#define STG_A(tt) do { int b_ = (tt) & 3; int ko_ = (tt) * 32;                          \
    __builtin_amdgcn_global_load_lds(AS1(gA0 + ko_), AS3(lA0 + b_ * 8192), 16, 0, 0);   \
    __builtin_amdgcn_global_load_lds(AS1(gA1 + ko_), AS3(lA1 + b_ * 8192), 16, 0, 0); } while (0)
#define STG_B(tt) do { int b_ = (tt) & 3; int ko_ = (tt) * 32;                          \
    __builtin_amdgcn_global_load_lds(AS1(gB0 + ko_), AS3(lB0 + b_ * 8192), 16, 0, 0);   \
    __builtin_amdgcn_global_load_lds(AS1(gB1 + ko_), AS3(lB1 + b_ * 8192), 16, 0, 0); } while (0)

    STG_A(0); STG_B(0);
    STG_A(1); STG_B(1);
    STG_A(2); STG_B(2);

    int fm = l & 31, cc = l >> 5;
    int sw = (fm >> 1) & 3;
    int pc0 = ((0 + cc) ^ sw) * 8;
    int pc1 = ((2 + cc) ^ sw) * 8;
    int aB  = (wr * 128 + fm) * 32;
    int bB  = (wc * 64 + fm) * 32 + 32768;

    for (int t = 0; t < NT; ++t) {
        if (t + 3 <= NT)
            asm volatile("s_waitcnt vmcnt(8)\n\ts_barrier" ::: "memory");
        else if (t + 2 <= NT)
            asm volatile("s_waitcnt vmcnt(4)\n\ts_barrier" ::: "memory");
        else
            asm volatile("s_waitcnt vmcnt(0)\n\ts_barrier" ::: "memory");

        const __bf16* base = lds + (t & 3) * 8192;

        bf16x8 a0[2][2], bfr[2][2];
        a0[0][0]  = *(const bf16x8*)(base + aB + 0 * 1024 + pc0);
        a0[0][1]  = *(const bf16x8*)(base + aB + 0 * 1024 + pc1);
        a0[1][0]  = *(const bf16x8*)(base + aB + 1 * 1024 + pc0);
        a0[1][1]  = *(const bf16x8*)(base + aB + 1 * 1024 + pc1);
        bfr[0][0] = *(const bf16x8*)(base + bB + 0 * 1024 + pc0);
        bfr[0][1] = *(const bf16x8*)(base + bB + 0 * 1024 + pc1);
        bfr[1][0] = *(const bf16x8*)(base + bB + 1 * 1024 + pc0);
        bfr[1][1] = *(const bf16x8*)(base + bB + 1 * 1024 + pc1);
        if (t + 3 < NT) STG_A(t + 3);
        __builtin_amdgcn_s_barrier();
        asm volatile("s_waitcnt lgkmcnt(0)" ::: "memory");
        __builtin_amdgcn_sched_barrier(0);
        __builtin_amdgcn_s_setprio(1);
#pragma unroll
        for (int u = 0; u < 2; ++u)
#pragma unroll
            for (int i = 0; i < 2; ++i)
#pragma unroll
                for (int j = 0; j < 2; ++j)
                    acc[i][j] = __builtin_amdgcn_mfma_f32_32x32x16_bf16(
                        a0[i][u], bfr[j][u], acc[i][j], 0, 0, 0);
        __builtin_amdgcn_s_setprio(0);

        bf16x8 a1[2][2];
        a1[0][0] = *(const bf16x8*)(base + aB + 2 * 1024 + pc0);
        a1[0][1] = *(const bf16x8*)(base + aB + 2 * 1024 + pc1);
        a1[1][0] = *(const bf16x8*)(base + aB + 3 * 1024 + pc0);
        a1[1][1] = *(const bf16x8*)(base + aB + 3 * 1024 + pc1);
        if (t + 3 < NT) STG_B(t + 3);
        __builtin_amdgcn_s_barrier();
        asm volatile("s_waitcnt lgkmcnt(0)" ::: "memory");
        __builtin_amdgcn_sched_barrier(0);
        __builtin_amdgcn_s_setprio(1);
#pragma unroll
        for (int u = 0; u < 2; ++u)
#pragma unroll
            for (int i = 0; i < 2; ++i)
#pragma unroll
                for (int j = 0; j < 2; ++j)
                    acc[2 + i][j] = __builtin_amdgcn_mfma_f32_32x32x16_bf16(
                        a1[i][u], bfr[j][u], acc[2 + i][j], 0, 0, 0);
        __builtin_amdgcn_s_setprio(0);
    }
#undef STG_A
#undef STG_B
}

// ---------------------------------------------------------------------------
// 256-tile GEMM with bias/ReLU epilogue (W1). Grid: (M/256, N/256), 512 thr.
// ---------------------------------------------------------------------------
template <bool BIAS, bool RELU>
__global__ __launch_bounds__(512, 2) void mgemm256(const __bf16* __restrict__ A,
                                                   const __bf16* __restrict__ Bt,
                                                   const float* __restrict__ bias,
                                                   __bf16* __restrict__ C,
                                                   int N, int Kstride) {
    int tid = threadIdx.x;
    int l = tid & 63, w = tid >> 6;
    int wr = w >> 2, wc = w & 3;
    int m0 = blockIdx.x * 256, n0 = blockIdx.y * 256;
    floatx16 acc[4][2] = {};
    mfma_core256<1024>(A, Bt, Kstride, 0, m0, n0, tid, acc);
#pragma unroll
    for (int i = 0; i < 4; ++i)
#pragma unroll
        for (int j = 0; j < 2; ++j) {
            int col  = n0 + wc * 64 + j * 32 + (l & 31);
            int rowb = m0 + wr * 128 + i * 32 + 4 * (l >> 5);
            float bv = 0.0f;
            if (BIAS) bv = bias[col];
#pragma unroll
            for (int reg = 0; reg < 16; ++reg) {
                int row = rowb + (reg & 3) + 8 * (reg >> 2);
                float v = acc[i][j][reg] + bv;
                if (RELU) v = fmaxf(v, 0.0f);
                C[(size_t)row * N + col] = (__bf16)v;
            }
        }
}

// ---------------------------------------------------------------------------
// 256-tile split-K GEMM (W2, KLEN=1024): z picks K chunk; bf16 partials.
// ---------------------------------------------------------------------------
template <int KLEN>
__global__ __launch_bounds__(512, 2) void mgemm256_sk(const __bf16* __restrict__ A,
                                                      const __bf16* __restrict__ Bt,
                                                      __bf16* __restrict__ P0,
                                                      __bf16* __restrict__ P3,
                                                      int M, int N, int Kstride) {
    int z = blockIdx.z;
    __bf16* C = (z == 3) ? P3 : (P0 + (size_t)z * M * N);
    int tid = threadIdx.x;
    int l = tid & 63, w = tid >> 6;
    int wr = w >> 2, wc = w & 3;
    int m0 = blockIdx.x * 256, n0 = blockIdx.y * 256;
    floatx16 acc[4][2] = {};
    mfma_core256<KLEN>(A, Bt, Kstride, z * KLEN, m0, n0, tid, acc);
#pragma unroll
    for (int i = 0; i < 4; ++i)
#pragma unroll
        for (int j = 0; j < 2; ++j) {
            int col  = n0 + wc * 64 + j * 32 + (l & 31);
            int rowb = m0 + wr * 128 + i * 32 + 4 * (l >> 5);
#pragma unroll
            for (int reg = 0; reg < 16; ++reg) {
                int row = rowb + (reg & 3) + 8 * (reg >> 2);
                C[(size_t)row * N + col] = (__bf16)acc[i][j][reg];
            }
        }
}

// ---------------------------------------------------------------------------
// 256-tile QKV GEMM: q,k columns to qkv[4096][3072]; v columns written only
// as transposed Vt[bh][d][T]. Grid: (16, 12), 512 thr.
// ---------------------------------------------------------------------------
__global__ __launch_bounds__(512, 2) void mgemm256_qkv(const __bf16* __restrict__ A,
                                                       const __bf16* __restrict__ Bt,
                                                       __bf16* __restrict__ C,
                                                       __bf16* __restrict__ Vt) {
    const int N = 3072;
    int tid = threadIdx.x;
    int l = tid & 63, w = tid >> 6;
    int wr = w >> 2, wc = w & 3;
    int m0 = blockIdx.x * 256, n0 = blockIdx.y * 256;
    floatx16 acc[4][2] = {};
    mfma_core256<1024>(A, Bt, 1024, 0, m0, n0, tid, acc);
#pragma unroll
    for (int i = 0; i < 4; ++i)
#pragma unroll
        for (int j = 0; j < 2; ++j) {
            int col  = n0 + wc * 64 + j * 32 + (l & 31);
            int rowb = m0 + wr * 128 + i * 32 + 4 * (l >> 5);
            if (col < 2048) {
#pragma unroll
                for (int reg = 0; reg < 16; ++reg) {
                    int row = rowb + (reg & 3) + 8 * (reg >> 2);
                    C[(size_t)row * N + col] = (__bf16)acc[i][j][reg];
                }
            } else {
                int vcol = col - 2048;
                int hh = vcol >> 6, dd = vcol & 63;
#pragma unroll
                for (int rq = 0; rq < 4; rq++) {
                    int row0 = rowb + 8 * rq;
                    int bb = row0 >> 11;
                    int tt = row0 & 2047;
                    bf16x4 pack;
                    pack[0] = (__bf16)acc[i][j][4 * rq + 0];
                    pack[1] = (__bf16)acc[i][j][4 * rq + 1];
                    pack[2] = (__bf16)acc[i][j][4 * rq + 2];
                    pack[3] = (__bf16)acc[i][j][4 * rq + 3];
                    *(bf16x4*)&Vt[(((size_t)bb * 16 + hh) * 64 + dd) * SEQ + tt] = pack;
                }
            }
        }
}

// ---------------------------------------------------------------------------
// MFMA flash attention (verified R5 config, 43.8 us): single-buffered K/V,
// no-max exp2 softmax, ones-MFMA l, K/V register prefetch, setprio.
// [dbuf variant measured slower: 47.7 us R6 — do not reintroduce]
// ---------------------------------------------------------------------------
__global__ __launch_bounds__(256) void attn_mfma(const __bf16* __restrict__ qkv,
                                                 const __bf16* __restrict__ Vt,
                                                 __bf16* __restrict__ ctx) {
    __shared__ __bf16 Ks[64 * 64];
    __shared__ __bf16 Vs[64 * 64];
    __shared__ __bf16 Ps[4][16 * 64];
    const int QKVW = 3 * HIDDEN;

    int bh = blockIdx.x;
    int qt = gridDim.y - 1 - blockIdx.y;
    int b = bh >> 4, h = bh & 15;
    int tid = threadIdx.x;
    int lane = tid & 63;
    int w = tid >> 6;
    int m = lane & 15;
    int g = lane >> 4;

    const float QSC = 1.44269504f / 8.0f;
    bf16x8 qf[2];
    {
        const __bf16* Qp = qkv + (size_t)(b * SEQ + qt * 64 + w * 16 + m) * QKVW
                         + h * HDIM + g * 8;
        qf[0] = *(const bf16x8*)(Qp);
        qf[1] = *(const bf16x8*)(Qp + 32);
#pragma unroll
        for (int t = 0; t < 2; t++)
#pragma unroll
            for (int i = 0; i < 8; i++)
                qf[t][i] = (__bf16)((float)qf[t][i] * QSC);
    }

    bf16x8 onesf;
#pragma unroll
    for (int i = 0; i < 8; i++) onesf[i] = (__bf16)1.0f;

    floatx4 oacc[4] = {};
    floatx4 lacc = {};

    int srow = tid >> 2;
    int sc0  = (tid & 3) * 2;
    const __bf16* Kg = qkv + (size_t)(b * SEQ) * QKVW + HIDDEN + h * HDIM;
    const __bf16* Vg = Vt + (size_t)bh * HDIM * SEQ;

    bf16x8 pk0, pk1, pv0, pv1;
    {
        const __bf16* kp = Kg + (size_t)srow * QKVW + sc0 * 8;
        pk0 = *(const bf16x8*)kp;
        pk1 = *(const bf16x8*)(kp + 8);
        const __bf16* vp = Vg + (size_t)srow * SEQ + sc0 * 8;
        pv0 = *(const bf16x8*)vp;
        pv1 = *(const bf16x8*)(vp + 8);
    }

    for (int kt = 0; kt <= qt; kt++) {
        __syncthreads();
        *(bf16x8*)&Ks[srow * 64 + SWZ(srow, sc0)]     = pk0;
        *(bf16x8*)&Ks[srow * 64 + SWZ(srow, sc0 + 1)] = pk1;
        *(bf16x8*)&Vs[srow * 64 + SWZ(srow, sc0)]     = pv0;
        *(bf16x8*)&Vs[srow * 64 + SWZ(srow, sc0 + 1)] = pv1;
        __syncthreads();

        if (kt < qt) {
            const __bf16* kp = Kg + (size_t)((kt + 1) * 64 + srow) * QKVW + sc0 * 8;
            pk0 = *(const bf16x8*)kp;
            pk1 = *(const bf16x8*)(kp + 8);
            const __bf16* vp = Vg + (size_t)srow * SEQ + (kt + 1) * 64 + sc0 * 8;
            pv0 = *(const bf16x8*)vp;
            pv1 = *(const bf16x8*)(vp + 8);
        }

        floatx4 sacc[4] = {};
        __builtin_amdgcn_s_setprio(1);
#pragma unroll
        for (int j = 0; j < 4; j++) {
#pragma unroll
            for (int t = 0; t < 2; t++) {
                int kr = 16 * j + m;
                bf16x8 kf = *(const bf16x8*)&Ks[kr * 64 + SWZ(kr, g + 4 * t)];
                sacc[j] = __builtin_amdgcn_mfma_f32_16x16x32_bf16(
                    qf[t], kf, sacc[j], 0, 0, 0);
            }
        }
        __builtin_amdgcn_s_setprio(0);

        if (kt == qt) {
            int qlocal = w * 16 + 4 * g;
#pragma unroll
            for (int j = 0; j < 4; j++)
#pragma unroll
                for (int r = 0; r < 4; r++)
                    if (16 * j + m > qlocal + r) sacc[j][r] = -INFINITY;
        }

        __bf16* Pw = &Ps[w][0];
#pragma unroll
        for (int j = 0; j < 4; j++)
#pragma unroll
            for (int r = 0; r < 4; r++) {
                float p = exp2f(sacc[j][r]);
                int row = 4 * g + r;
                int key = 16 * j + m;
                Pw[row * 64 + SWZ(row, key >> 3) + (key & 7)] = (__bf16)p;
            }

        __builtin_amdgcn_s_setprio(1);
#pragma unroll
        for (int t = 0; t < 2; t++) {
            bf16x8 pf = *(const bf16x8*)&Pw[m * 64 + SWZ(m, g + 4 * t)];
            lacc = __builtin_amdgcn_mfma_f32_16x16x32_bf16(pf, onesf, lacc, 0, 0, 0);
#pragma unroll
            for (int jd = 0; jd < 4; jd++) {
                int vr = 16 * jd + m;
                bf16x8 vf = *(const bf16x8*)&Vs[vr * 64 + SWZ(vr, g + 4 * t)];
                oacc[jd] = __builtin_amdgcn_mfma_f32_16x16x32_bf16(
                    pf, vf, oacc[jd], 0, 0, 0);
            }
        }
        __builtin_amdgcn_s_setprio(0);
    }

#pragma unroll
    for (int r = 0; r < 4; r++) {
        float invl = 1.0f / lacc[r];
        int row = qt * 64 + w * 16 + 4 * g + r;
        __bf16* cp = ctx + (size_t)(b * SEQ + row) * HIDDEN + h * HDIM;
#pragma unroll
        for (int jd = 0; jd < 4; jd++)
            cp[16 * jd + m] = (__bf16)(oacc[jd][r] * invl);
    }
}

// ---------------------------------------------------------------------------
extern "C" void kernel_launch(void* const* d_in, const int* in_sizes, int n_in,
                              void* d_out, int out_size, void* d_ws, size_t ws_size,
                              hipStream_t stream) {
    (void)in_sizes; (void)n_in; (void)out_size; (void)ws_size;
    const float* emb = (const float*)d_in[0];
    const float* Wq  = (const float*)d_in[1];
    const float* Wk  = (const float*)d_in[2];
    const float* Wv  = (const float*)d_in[3];
    const float* Wo  = (const float*)d_in[4];
    const float* W1  = (const float*)d_in[5];
    const float* b1  = (const float*)d_in[6];
    const float* W2  = (const float*)d_in[7];
    const float* b2  = (const float*)d_in[8];
    const float* g1  = (const float*)d_in[9];
    const float* be1 = (const float*)d_in[10];
    const float* g2  = (const float*)d_in[11];
    const float* be2 = (const float*)d_in[12];
    float* out = (float*)d_out;

    // ws layout (bf16 elems; ME = 1M elems = 2MB). Total 36 ME = 72 MB.
    //   [0,4)   h (LN1) -> ctx (attn out) -> ff1 head
    //   [4,16)  qkv (q,k cols used) -> Wo partials [4,12) -> ff1
    //   [16,20) h2 -> W2 partial z0
    //   [20,24) BtQKV+BtO -> W2 partial z1
    //   [24,28) Bt1 -> W2 partial z2
    //   [28,32) Bt2 (alive through W2 gemm)
    //   [32,36) Vt -> W2 partial z3
    __bf16* wsb = (__bf16*)d_ws;
    const size_t ME = 1024 * 1024;
    __bf16* h     = wsb;
    __bf16* qkv   = wsb + 4 * ME;
    __bf16* ctx   = wsb;
    __bf16* ff1   = wsb;
    __bf16* h2    = wsb + 16 * ME;
    __bf16* BtQKV = wsb + 20 * ME;
    __bf16* BtO   = wsb + 23 * ME;
    __bf16* Bt1   = wsb + 24 * ME;
    __bf16* Bt2   = wsb + 28 * ME;
    __bf16* Vt    = wsb + 32 * ME;
    __bf16* woP   = wsb + 4 * ME;    // 2 x 4 ME
    __bf16* w2P0  = wsb + 16 * ME;   // z0..z2 contiguous (12 ME)
    __bf16* w2P3  = wsb + 32 * ME;   // z3

    prep_all<<<16384, 256, 0, stream>>>(Wq, Wk, Wv, Wo, W1, W2,
                                        BtQKV, BtO, Bt1, Bt2,
                                        emb, g1, be1, h);

    mgemm256_qkv<<<dim3(16, 12), 512, 0, stream>>>(h, BtQKV, qkv, Vt);

    attn_mfma<<<dim3(32, 32), 256, 0, stream>>>(qkv, Vt, ctx);

    // Wo split-K x2 on the legacy 128-tile core, bf16 partials
    mgemm_sk<<<dim3(32, 8, 2), 256, 0, stream>>>(
        ctx, BtO, woP, nullptr, ROWS, 1024, 1024, 512);
    red_wo_ln<<<ROWS, 256, 0, stream>>>(emb, woP, woP + 4 * ME, g2, be2, out, h2);

    mgemm256<true, true><<<dim3(16, 16), 512, 0, stream>>>(
        h2, Bt1, b1, ff1, 4096, 1024);

    // W2 split-K x4 on the 256-tile core, bf16 partials
    mgemm256_sk<1024><<<dim3(16, 4, 4), 512, 0, stream>>>(
        ff1, Bt2, w2P0, w2P3, ROWS, 1024, 4096);
    red_w2<<<2048, 256, 0, stream>>>(w2P0, w2P3, b2, out, 1024);
}

// Round 11
// 307.912 us; speedup vs baseline: 1.0251x; 1.0158x over previous
//
#include <hip/hip_runtime.h>
#include <math.h>

#define HIDDEN 1024
#define SEQ    2048
#define NHEAD  16
#define HDIM   64
#define ROWS   (2 * SEQ)

typedef float  floatx4  __attribute__((ext_vector_type(4)));
typedef float  floatx16 __attribute__((ext_vector_type(16)));
typedef __bf16 bf16x8   __attribute__((ext_vector_type(8)));
typedef __bf16 bf16x4   __attribute__((ext_vector_type(4)));

#define AS1(p) ((const __attribute__((address_space(1))) void*)(p))
#define AS3(p) ((__attribute__((address_space(3))) void*)(p))

// swizzled byte-chunk offset (in elements): 16B chunks XOR'd by row&7 (attn)
#define SWZ(row, chunk) ((((chunk) ^ ((row) & 7)) * 8))

// [R7: XCD swizzle regressed. R8: STG-before-reads regressed. R9: wall noise
//  ±10us. R10: 4-phase core on all GEMMs -> container failed (flake or hang);
//  this round bisects: 4-phase on W1 only, verified 2-phase elsewhere.]

// ---------------------------------------------------------------------------
// Prep launch: 6 weight converts + LayerNorm1, one kernel.
// ---------------------------------------------------------------------------
__global__ __launch_bounds__(256) void prep_all(const float* __restrict__ Wq,
                                                const float* __restrict__ Wk,
                                                const float* __restrict__ Wv,
                                                const float* __restrict__ Wo,
                                                const float* __restrict__ W1,
                                                const float* __restrict__ W2,
                                                __bf16* __restrict__ BtQKV,
                                                __bf16* __restrict__ BtO,
                                                __bf16* __restrict__ Bt1,
                                                __bf16* __restrict__ Bt2,
                                                const float* __restrict__ emb,
                                                const float* __restrict__ g1,
                                                const float* __restrict__ be1,
                                                __bf16* __restrict__ h) {
    int id = blockIdx.x;
    int tid = threadIdx.x;
    if (id >= 12288) {
        // ---- LayerNorm1 row ----
        int row = id - 12288;
        size_t i = (size_t)row * HIDDEN + tid * 4;
        float4 v = *(const float4*)(emb + i);
        float s  = v.x + v.y + v.z + v.w;
        float s2 = v.x * v.x + v.y * v.y + v.z * v.z + v.w * v.w;
#pragma unroll
        for (int off = 1; off < 64; off <<= 1) {
            s  += __shfl_xor(s, off, 64);
            s2 += __shfl_xor(s2, off, 64);
        }
        __shared__ float red[8];
        int wid = tid >> 6;
        if ((tid & 63) == 0) { red[wid] = s; red[wid + 4] = s2; }
        __syncthreads();
        s  = red[0] + red[1] + red[2] + red[3];
        s2 = red[4] + red[5] + red[6] + red[7];
        float mu  = s * (1.0f / HIDDEN);
        float var = fmaxf(s2 * (1.0f / HIDDEN) - mu * mu, 0.0f);
        float inv = rsqrtf(var + 1e-5f);
        float4 gv = *(const float4*)(g1 + tid * 4);
        float4 bv = *(const float4*)(be1 + tid * 4);
        bf16x4 o;
        o[0] = (__bf16)((v.x - mu) * inv * gv.x + bv.x);
        o[1] = (__bf16)((v.y - mu) * inv * gv.y + bv.y);
        o[2] = (__bf16)((v.z - mu) * inv * gv.z + bv.z);
        o[3] = (__bf16)((v.w - mu) * inv * gv.w + bv.w);
        *(bf16x4*)(h + i) = o;
        return;
    }
    // ---- weight convert tile (32x32) ----
    __shared__ float t[32][33];
    const float* in; __bf16* out; int K, N, nt, kt;
    if (id < 4096) {
        int job = id >> 10, tt = id & 1023;
        nt = tt & 31; kt = tt >> 5; K = 1024; N = 1024;
        if (job == 0)      { in = Wq; out = BtQKV; }
        else if (job == 1) { in = Wk; out = BtQKV + 1024 * 1024; }
        else if (job == 2) { in = Wv; out = BtQKV + 2 * 1024 * 1024; }
        else               { in = Wo; out = BtO; }
    } else if (id < 8192) {
        int tt = id - 4096;
        nt = tt & 127; kt = tt >> 7; K = 1024; N = 4096; in = W1; out = Bt1;
    } else {
        int tt = id - 8192;
        nt = tt & 31; kt = tt >> 5; K = 4096; N = 1024; in = W2; out = Bt2;
    }
    bool frag = (id >= 3072 && id < 4096);    // only Wo keeps fragment-major
    int n0 = nt * 32, k0 = kt * 32;
    int r  = tid >> 3;             // n within tile
    int c4 = (tid & 7) * 4;        // k run of 4
    float4 v = *(const float4*)(in + (size_t)(k0 + r) * N + n0 + c4);
    t[r][c4 + 0] = v.x; t[r][c4 + 1] = v.y; t[r][c4 + 2] = v.z; t[r][c4 + 3] = v.w;
    __syncthreads();
    bf16x4 o;
    o[0] = (__bf16)t[c4 + 0][r];
    o[1] = (__bf16)t[c4 + 1][r];
    o[2] = (__bf16)t[c4 + 2][r];
    o[3] = (__bf16)t[c4 + 3][r];
    int n = n0 + r, k = k0 + c4;
    if (!frag) {
        *(bf16x4*)(out + (size_t)n * K + k) = o;
    } else {
        size_t blk = (size_t)(n >> 5) * (K >> 4) + (k >> 4);
        int ln = ((k >> 3) & 1) * 32 + (n & 31);
        *(bf16x4*)(out + blk * 512 + ln * 8 + (k & 7)) = o;
    }
}

// ---------------------------------------------------------------------------
// Fused Wo-split-K(x2) reduction + residual + LayerNorm2.
// ---------------------------------------------------------------------------
__global__ __launch_bounds__(256) void red_wo_ln(const float* __restrict__ emb,
                                                 const __bf16* __restrict__ p0,
                                                 const __bf16* __restrict__ p1,
                                                 const float* __restrict__ g,
                                                 const float* __restrict__ beta,
                                                 float* __restrict__ out,
                                                 __bf16* __restrict__ h2) {
    int row = blockIdx.x;
    int tid = threadIdx.x;
    size_t i = (size_t)row * HIDDEN + tid * 4;
    float4 e = *(const float4*)(emb + i);
    bf16x4 a = *(const bf16x4*)(p0 + i);
    bf16x4 b = *(const bf16x4*)(p1 + i);
    float4 v;
    v.x = e.x + (float)a[0] + (float)b[0];
    v.y = e.y + (float)a[1] + (float)b[1];
    v.z = e.z + (float)a[2] + (float)b[2];
    v.w = e.w + (float)a[3] + (float)b[3];
    *(float4*)(out + i) = v;

    float s  = v.x + v.y + v.z + v.w;
    float s2 = v.x * v.x + v.y * v.y + v.z * v.z + v.w * v.w;
#pragma unroll
    for (int off = 1; off < 64; off <<= 1) {
        s  += __shfl_xor(s, off, 64);
        s2 += __shfl_xor(s2, off, 64);
    }
    __shared__ float red[8];
    int wid = tid >> 6;
    if ((tid & 63) == 0) { red[wid] = s; red[wid + 4] = s2; }
    __syncthreads();
    s  = red[0] + red[1] + red[2] + red[3];
    s2 = red[4] + red[5] + red[6] + red[7];
    float mu  = s * (1.0f / HIDDEN);
    float var = fmaxf(s2 * (1.0f / HIDDEN) - mu * mu, 0.0f);
    float inv = rsqrtf(var + 1e-5f);
    float4 gv = *(const float4*)(g + tid * 4);
    float4 bv = *(const float4*)(beta + tid * 4);
    bf16x4 o;
    o[0] = (__bf16)((v.x - mu) * inv * gv.x + bv.x);
    o[1] = (__bf16)((v.y - mu) * inv * gv.y + bv.y);
    o[2] = (__bf16)((v.z - mu) * inv * gv.z + bv.z);
    o[3] = (__bf16)((v.w - mu) * inv * gv.w + bv.w);
    *(bf16x4*)(h2 + i) = o;
}

// ---------------------------------------------------------------------------
// W2 reduction: out += p0+p1+p2+p3 + b2[col]
// ---------------------------------------------------------------------------
__global__ __launch_bounds__(256) void red_w2(const __bf16* __restrict__ p0,
                                              const __bf16* __restrict__ p3,
                                              const float* __restrict__ b2,
                                              float* __restrict__ out,
                                              int N) {
    size_t i = ((size_t)blockIdx.x * 256 + threadIdx.x) * 8;
    const size_t MN = (size_t)ROWS * HIDDEN;
    bf16x8 a = *(const bf16x8*)(p0 + i);
    bf16x8 b = *(const bf16x8*)(p0 + MN + i);
    bf16x8 c = *(const bf16x8*)(p0 + 2 * MN + i);
    bf16x8 d = *(const bf16x8*)(p3 + i);
    int col = (int)(i & (size_t)(N - 1));
    float4 bb0 = *(const float4*)(b2 + col);
    float4 bb1 = *(const float4*)(b2 + col + 4);
    float4 o0 = *(const float4*)(out + i);
    float4 o1 = *(const float4*)(out + i + 4);
    o0.x += (float)a[0] + (float)b[0] + (float)c[0] + (float)d[0] + bb0.x;
    o0.y += (float)a[1] + (float)b[1] + (float)c[1] + (float)d[1] + bb0.y;
    o0.z += (float)a[2] + (float)b[2] + (float)c[2] + (float)d[2] + bb0.z;
    o0.w += (float)a[3] + (float)b[3] + (float)c[3] + (float)d[3] + bb0.w;
    o1.x += (float)a[4] + (float)b[4] + (float)c[4] + (float)d[4] + bb1.x;
    o1.y += (float)a[5] + (float)b[5] + (float)c[5] + (float)d[5] + bb1.y;
    o1.z += (float)a[6] + (float)b[6] + (float)c[6] + (float)d[6] + bb1.z;
    o1.w += (float)a[7] + (float)b[7] + (float)c[7] + (float)d[7] + bb1.w;
    *(float4*)(out + i)     = o0;
    *(float4*)(out + i + 4) = o1;
}

// ---------------------------------------------------------------------------
// Legacy 128x128 MFMA core (Wo split-K only — short-K regime winner).
// ---------------------------------------------------------------------------
__device__ __forceinline__ void mfma_core128(const __bf16* __restrict__ A,
                                             const __bf16* __restrict__ BtF,
                                             int Kstride, int kbase, int Klen,
                                             int m0, int n0, int tid,
                                             floatx16 (&acc)[2][2]) {
    __shared__ __bf16 As[2 * 128 * 32];
    const int BUF = 128 * 32;
    int lane = tid & 63;
    int wave = tid >> 6;
    int wr = wave >> 1, wc = wave & 1;

    int sr = lane >> 2;
    int sk = 8 * ((lane & 3) ^ ((sr >> 1) & 3));
    const __bf16* ga0 = A + (size_t)(m0 + wave * 16 + sr) * Kstride + kbase + sk;
    const __bf16* ga1 = ga0 + (size_t)64 * Kstride;
    __bf16* la0 = &As[wave * 512];
    __bf16* la1 = &As[2048 + wave * 512];

    int fm = lane & 31;
    int gswz = (lane >> 1) & 3;
    int slot0 = ((lane >> 5) + 0) ^ gswz;
    int slot1 = ((lane >> 5) + 2) ^ gswz;

    const __bf16* bb = BtF + ((size_t)((n0 >> 5) + wc * 2) * (Kstride >> 4)) * 512
                     + (size_t)lane * 8;
    const size_t jstr = (size_t)(Kstride >> 4) * 512;
    int ci0 = kbase >> 4;

    __builtin_amdgcn_global_load_lds(AS1(ga0), AS3(la0), 16, 0, 0);
    __builtin_amdgcn_global_load_lds(AS1(ga1), AS3(la1), 16, 0, 0);
    bf16x8 bcur[2][2], bnxt[2][2];
#pragma unroll
    for (int j = 0; j < 2; j++)
#pragma unroll
        for (int t = 0; t < 2; t++)
            bcur[j][t] = *(const bf16x8*)(bb + j * jstr + (size_t)(ci0 + t) * 512);

    int buf = 0;
    for (int k0 = 0; k0 < Klen; k0 += 32, buf ^= 1) {
        __syncthreads();
        if (k0 + 32 < Klen) {
            int nb = (buf ^ 1) * BUF;
            __builtin_amdgcn_global_load_lds(AS1(ga0 + k0 + 32), AS3(la0 + nb), 16, 0, 0);
            __builtin_amdgcn_global_load_lds(AS1(ga1 + k0 + 32), AS3(la1 + nb), 16, 0, 0);
            int ci = ci0 + ((k0 + 32) >> 4);
#pragma unroll
            for (int j = 0; j < 2; j++)
#pragma unroll
                for (int t = 0; t < 2; t++)
                    bnxt[j][t] = *(const bf16x8*)(bb + j * jstr + (size_t)(ci + t) * 512);
        }
        const __bf16* Ab = As + buf * BUF;
        bf16x8 af[2][2];
#pragma unroll
        for (int i = 0; i < 2; i++) {
            const __bf16* rp = Ab + (size_t)(wr * 64 + i * 32 + fm) * 32;
            af[i][0] = *(const bf16x8*)(rp + slot0 * 8);
            af[i][1] = *(const bf16x8*)(rp + slot1 * 8);
        }
#pragma unroll
        for (int t = 0; t < 2; t++)
#pragma unroll
            for (int i = 0; i < 2; i++)
#pragma unroll
                for (int j = 0; j < 2; j++)
                    acc[i][j] = __builtin_amdgcn_mfma_f32_32x32x16_bf16(
                        af[i][t], bcur[j][t], acc[i][j], 0, 0, 0);
#pragma unroll
        for (int j = 0; j < 2; j++)
#pragma unroll
            for (int t = 0; t < 2; t++)
                bcur[j][t] = bnxt[j][t];
    }
}

// ---------------------------------------------------------------------------
// Split-K GEMM on the legacy core (Wo only; z in {0,1}).
// ---------------------------------------------------------------------------
__global__ __launch_bounds__(256) void mgemm_sk(const __bf16* __restrict__ A,
                                                const __bf16* __restrict__ BtF,
                                                __bf16* __restrict__ P0,
                                                __bf16* __restrict__ P3,
                                                int M, int N, int Kstride, int Klen) {
    int z = blockIdx.z;
    __bf16* C = (z == 3) ? P3 : (P0 + (size_t)z * M * N);
    int tid = threadIdx.x;
    int lane = tid & 63;
    int wave = tid >> 6;
    int m0 = blockIdx.x * 128, n0 = blockIdx.y * 128;
    int wr = wave >> 1, wc = wave & 1;
    floatx16 acc[2][2] = {};
    mfma_core128(A, BtF, Kstride, z * Klen, Klen, m0, n0, tid, acc);

#pragma unroll
    for (int i = 0; i < 2; i++) {
#pragma unroll
        for (int j = 0; j < 2; j++) {
            int col  = n0 + wc * 64 + j * 32 + (lane & 31);
            int rowb = m0 + wr * 64 + i * 32 + 4 * (lane >> 5);
#pragma unroll
            for (int reg = 0; reg < 16; reg++) {
                int row = rowb + (reg & 3) + 8 * (reg >> 2);
                C[(size_t)row * N + col] = (__bf16)acc[i][j][reg];
            }
        }
    }
}

// ---------------------------------------------------------------------------
// 256x256 MFMA core v1 — verified 2-phase BK=32 ring-4 schedule (R2-R9).
// Used by QKV and W2 this round.
// ---------------------------------------------------------------------------
template <int KLEN>
__device__ __forceinline__ void mfma_core256(const __bf16* __restrict__ A,
                                             const __bf16* __restrict__ Bt,
                                             int Kstride, int kbase,
                                             int m0, int n0, int tid,
                                             floatx16 (&acc)[4][2]) {
    __shared__ __bf16 lds[8 * 8192];          // 128 KiB
    const int NT = KLEN >> 5;                 // K-tiles of 32 (NT >= 3)
    int l = tid & 63;
    int w = tid >> 6;
    int wr = w >> 2, wc = w & 3;

    int lr  = l >> 2;                                 // row within group
    int lcf = ((l & 3) ^ ((l >> 3) & 3)) * 8;         // pre-swizzled src chunk
    const __bf16* gA0 = A  + (size_t)(m0 + (w * 2 + 0) * 16 + lr) * Kstride + kbase + lcf;
    const __bf16* gA1 = A  + (size_t)(m0 + (w * 2 + 1) * 16 + lr) * Kstride + kbase + lcf;
    const __bf16* gB0 = Bt + (size_t)(n0 + (w * 2 + 0) * 16 + lr) * Kstride + kbase + lcf;
    const __bf16* gB1 = Bt + (size_t)(n0 + (w * 2 + 1) * 16 + lr) * Kstride + kbase + lcf;
    __bf16* lA0 = lds + (w * 2 + 0) * 512;
    __bf16* lA1 = lds + (w * 2 + 1) * 512;
    __bf16* lB0 = lA0 + 32768;
    __bf16* lB1 = lA1 + 32768;

#define STG_A(tt) do { int b_ = (tt) & 3; int ko_ = (tt) * 32;                          \
    __builtin_amdgcn_global_load_lds(AS1(gA0 + ko_), AS3(lA0 + b_ * 8192), 16, 0, 0);   \
    __builtin_amdgcn_global_load_lds(AS1(gA1 + ko_), AS3(lA1 + b_ * 8192), 16, 0, 0); } while (0)
#define STG_B(tt) do { int b_ = (tt) & 3; int ko_ = (tt) * 32;                          \
    __builtin_amdgcn_global_load_lds(AS1(gB0 + ko_), AS3(lB0 + b_ * 8192), 16, 0, 0);   \
    __builtin_amdgcn_global_load_lds(AS1(gB1 + ko_), AS3(lB1 + b_ * 8192), 16, 0, 0); } while (0)

    STG_A(0); STG_B(0);
    STG_A(1); STG_B(1);
    STG_A(2); STG_B(2);

    int fm = l & 31, cc = l >> 5;
    int sw = (fm >> 1) & 3;
    int pc0 = ((0 + cc) ^ sw) * 8;
    int pc1 = ((2 + cc) ^ sw) * 8;
    int aB  = (wr * 128 + fm) * 32;
    int bB  = (wc * 64 + fm) * 32 + 32768;

    for (int t = 0; t < NT; ++t) {
        if (t + 3 <= NT)
            asm volatile("s_waitcnt vmcnt(8)\n\ts_barrier" ::: "memory");
        else if (t + 2 <= NT)
            asm volatile("s_waitcnt vmcnt(4)\n\ts_barrier" ::: "memory");
        else
            asm volatile("s_waitcnt vmcnt(0)\n\ts_barrier" ::: "memory");

        const __bf16* base = lds + (t & 3) * 8192;

        bf16x8 a0[2][2], bfr[2][2];
        a0[0][0]  = *(const bf16x8*)(base + aB + 0 * 1024 + pc0);
        a0[0][1]  = *(const bf16x8*)(base + aB + 0 * 1024 + pc1);
        a0[1][0]  = *(const bf16x8*)(base + aB + 1 * 1024 + pc0);
        a0[1][1]  = *(const bf16x8*)(base + aB + 1 * 1024 + pc1);
        bfr[0][0] = *(const bf16x8*)(base + bB + 0 * 1024 + pc0);
        bfr[0][1] = *(const bf16x8*)(base + bB + 0 * 1024 + pc1);
        bfr[1][0] = *(const bf16x8*)(base + bB + 1 * 1024 + pc0);
        bfr[1][1] = *(const bf16x8*)(base + bB + 1 * 1024 + pc1);
        if (t + 3 < NT) STG_A(t + 3);
        __builtin_amdgcn_s_barrier();
        asm volatile("s_waitcnt lgkmcnt(0)" ::: "memory");
        __builtin_amdgcn_sched_barrier(0);
        __builtin_amdgcn_s_setprio(1);
#pragma unroll
        for (int u = 0; u < 2; ++u)
#pragma unroll
            for (int i = 0; i < 2; ++i)
#pragma unroll
                for (int j = 0; j < 2; ++j)
                    acc[i][j] = __builtin_amdgcn_mfma_f32_32x32x16_bf16(
                        a0[i][u], bfr[j][u], acc[i][j], 0, 0, 0);
        __builtin_amdgcn_s_setprio(0);

        bf16x8 a1[2][2];
        a1[0][0] = *(const bf16x8*)(base + aB + 2 * 1024 + pc0);
        a1[0][1] = *(const bf16x8*)(base + aB + 2 * 1024 + pc1);
        a1[1][0] = *(const bf16x8*)(base + aB + 3 * 1024 + pc0);
        a1[1][1] = *(const bf16x8*)(base + aB + 3 * 1024 + pc1);
        if (t + 3 < NT) STG_B(t + 3);
        __builtin_amdgcn_s_barrier();
        asm volatile("s_waitcnt lgkmcnt(0)" ::: "memory");
        __builtin_amdgcn_sched_barrier(0);
        __builtin_amdgcn_s_setprio(1);
#pragma unroll
        for (int u = 0; u < 2; ++u)
#pragma unroll
            for (int i = 0; i < 2; ++i)
#pragma unroll
                for (int j = 0; j < 2; ++j)
                    acc[2 + i][j] = __builtin_amdgcn_mfma_f32_32x32x16_bf16(
                        a1[i][u], bfr[j][u], acc[2 + i][j], 0, 0, 0);
        __builtin_amdgcn_s_setprio(0);
    }
#undef STG_A
#undef STG_B
}

// ---------------------------------------------------------------------------
// 256x256 MFMA core v2 — 4-phase derived-waits (R10, under bisection; W1 only).
// Ledger: 2 loads/wave/phase uniform; ph0 vmcnt(3), ph1 4|2, ph2 5|1, ph3 6|0.
// ---------------------------------------------------------------------------
template <int KLEN>
__device__ __forceinline__ void mfma_core256p4(const __bf16* __restrict__ A,
                                               const __bf16* __restrict__ Bt,
                                               int Kstride, int kbase,
                                               int m0, int n0, int tid,
                                               floatx16 (&acc)[4][2]) {
    __shared__ __bf16 lds[65536];             // 128 KiB
    const int NS = KLEN >> 6;                 // K-steps of 64 (NS >= 2)
    int l = tid & 63;
    int w = tid >> 6;
    int wr = w >> 2, wc = w & 3;

    int srg = l >> 3;                          // row within 8-row group (0..7)
    int scf = ((l & 7) ^ srg) * 8;             // swizzled chunk offset (elems)
    const __bf16* gB = Bt + (size_t)(n0 + w * 16 + srg) * Kstride + kbase + scf;
    const __bf16* gA = A  + (size_t)(m0 + wr * 128 + (w & 3) * 8 + srg) * Kstride
                     + kbase + scf;
    __bf16* lBd = lds + 32768 + (w * 16) * 64 + l * 8;
    __bf16* lAd = lds + wr * 2048 + (w & 3) * 512 + l * 8;

#define STG_BH(tb, hb, kk) do {                                                          \
    __builtin_amdgcn_global_load_lds(AS1(gB + (size_t)(hb) * 128 * Kstride + (kk)),      \
                                     AS3(lBd + (tb) * 16384 + (hb) * 8192), 16, 0, 0);   \
    __builtin_amdgcn_global_load_lds(AS1(gB + (size_t)((hb) * 128 + 8) * Kstride + (kk)),\
                                     AS3(lBd + (tb) * 16384 + (hb) * 8192 + 512), 16, 0, 0); } while (0)
#define STG_AQ(tb, q, kk)                                                                \
    __builtin_amdgcn_global_load_lds(AS1(gA + (size_t)(q) * 32 * Kstride + (kk)),        \
                                     AS3(lAd + (tb) * 16384 + (q) * 4096), 16, 0, 0)

    int fm = l & 31, cc = l >> 5;
    int pc[4];
#pragma unroll
    for (int u = 0; u < 4; ++u) pc[u] = ((2 * u + cc) ^ (fm & 7)) * 8;
    int aOff = wr * 2048 + fm * 64;
    int bOff = 32768 + ((wc & 1) * 64 + fm) * 64 + (wc >> 1) * 8192;

    STG_BH(0, 0, 0); STG_BH(0, 1, 0);
    STG_AQ(0, 0, 0); STG_AQ(0, 1, 0); STG_AQ(0, 2, 0); STG_AQ(0, 3, 0);

    for (int S = 0; S < NS; ++S) {
        int b = S & 1, tb = b ^ 1;
        int kk = (S + 1) * 64;
        bool pf = (S + 1) < NS;
        const __bf16* aB_ = lds + b * 16384 + aOff;
        const __bf16* bB_ = lds + b * 16384 + bOff;

        bf16x8 bc[2][4];
        // ---- phase 0: acc[0][*] ----
        asm volatile("s_waitcnt vmcnt(3)\n\ts_barrier" ::: "memory");
        {
            bf16x8 a[4];
#pragma unroll
            for (int j = 0; j < 2; ++j)
#pragma unroll
                for (int u = 0; u < 4; ++u)
                    bc[j][u] = *(const bf16x8*)(bB_ + j * 2048 + pc[u]);
#pragma unroll
            for (int u = 0; u < 4; ++u)
                a[u] = *(const bf16x8*)(aB_ + 0 * 4096 + pc[u]);
            if (pf) STG_BH(tb, 0, kk);
            asm volatile("s_waitcnt lgkmcnt(0)" ::: "memory");
            __builtin_amdgcn_sched_barrier(0);
            __builtin_amdgcn_s_setprio(1);
#pragma unroll
            for (int u = 0; u < 4; ++u)
#pragma unroll
                for (int j = 0; j < 2; ++j)
                    acc[0][j] = __builtin_amdgcn_mfma_f32_32x32x16_bf16(
                        a[u], bc[j][u], acc[0][j], 0, 0, 0);
            __builtin_amdgcn_s_setprio(0);
        }
        // ---- phase 1: acc[1][*] ----
        if (pf) asm volatile("s_waitcnt vmcnt(4)\n\ts_barrier" ::: "memory");
        else    asm volatile("s_waitcnt vmcnt(2)\n\ts_barrier" ::: "memory");
        {
            bf16x8 a[4];
#pragma unroll
            for (int u = 0; u < 4; ++u)
                a[u] = *(const bf16x8*)(aB_ + 1 * 4096 + pc[u]);
            if (pf) STG_BH(tb, 1, kk);
            asm volatile("s_waitcnt lgkmcnt(0)" ::: "memory");
            __builtin_amdgcn_sched_barrier(0);
            __builtin_amdgcn_s_setprio(1);
#pragma unroll
            for (int u = 0; u < 4; ++u)
#pragma unroll
                for (int j = 0; j < 2; ++j)
                    acc[1][j] = __builtin_amdgcn_mfma_f32_32x32x16_bf16(
                        a[u], bc[j][u], acc[1][j], 0, 0, 0);
            __builtin_amdgcn_s_setprio(0);
        }
        // ---- phase 2: acc[2][*] ----
        if (pf) asm volatile("s_waitcnt vmcnt(5)\n\ts_barrier" ::: "memory");
        else    asm volatile("s_waitcnt vmcnt(1)\n\ts_barrier" ::: "memory");
        {
            bf16x8 a[4];
#pragma unroll
            for (int u = 0; u < 4; ++u)
                a[u] = *(const bf16x8*)(aB_ + 2 * 4096 + pc[u]);
            if (pf) { STG_AQ(tb, 0, kk); STG_AQ(tb, 1, kk); }
            asm volatile("s_waitcnt lgkmcnt(0)" ::: "memory");
            __builtin_amdgcn_sched_barrier(0);
            __builtin_amdgcn_s_setprio(1);
#pragma unroll
            for (int u = 0; u < 4; ++u)
#pragma unroll
                for (int j = 0; j < 2; ++j)
                    acc[2][j] = __builtin_amdgcn_mfma_f32_32x32x16_bf16(
                        a[u], bc[j][u], acc[2][j], 0, 0, 0);
            __builtin_amdgcn_s_setprio(0);
        }
        // ---- phase 3: acc[3][*] ----
        if (pf) asm volatile("s_waitcnt vmcnt(6)\n\ts_barrier" ::: "memory");
        else    asm volatile("s_waitcnt vmcnt(0)\n\ts_barrier" ::: "memory");
        {
            bf16x8 a[4];
#pragma unroll
            for (int u = 0; u < 4; ++u)
                a[u] = *(const bf16x8*)(aB_ + 3 * 4096 + pc[u]);
            if (pf) { STG_AQ(tb, 2, kk); STG_AQ(tb, 3, kk); }
            asm volatile("s_waitcnt lgkmcnt(0)" ::: "memory");
            __builtin_amdgcn_sched_barrier(0);
            __builtin_amdgcn_s_setprio(1);
#pragma unroll
            for (int u = 0; u < 4; ++u)
#pragma unroll
                for (int j = 0; j < 2; ++j)
                    acc[3][j] = __builtin_amdgcn_mfma_f32_32x32x16_bf16(
                        a[u], bc[j][u], acc[3][j], 0, 0, 0);
            __builtin_amdgcn_s_setprio(0);
        }
    }
#undef STG_BH
#undef STG_AQ
}

// ---------------------------------------------------------------------------
// 256-tile GEMM with bias/ReLU epilogue (W1) — on the v2 4-phase core.
// ---------------------------------------------------------------------------
template <bool BIAS, bool RELU>
__global__ __launch_bounds__(512, 2) void mgemm256(const __bf16* __restrict__ A,
                                                   const __bf16* __restrict__ Bt,
                                                   const float* __restrict__ bias,
                                                   __bf16* __restrict__ C,
                                                   int N, int Kstride) {
    int tid = threadIdx.x;
    int l = tid & 63, w = tid >> 6;
    int wr = w >> 2, wc = w & 3;
    int m0 = blockIdx.x * 256, n0 = blockIdx.y * 256;
    floatx16 acc[4][2] = {};
    mfma_core256p4<1024>(A, Bt, Kstride, 0, m0, n0, tid, acc);
#pragma unroll
    for (int i = 0; i < 4; ++i)
#pragma unroll
        for (int j = 0; j < 2; ++j) {
            int col  = n0 + wc * 64 + j * 32 + (l & 31);
            int rowb = m0 + wr * 128 + i * 32 + 4 * (l >> 5);
            float bv = 0.0f;
            if (BIAS) bv = bias[col];
#pragma unroll
            for (int reg = 0; reg < 16; ++reg) {
                int row = rowb + (reg & 3) + 8 * (reg >> 2);
                float v = acc[i][j][reg] + bv;
                if (RELU) v = fmaxf(v, 0.0f);
                C[(size_t)row * N + col] = (__bf16)v;
            }
        }
}

// ---------------------------------------------------------------------------
// 256-tile split-K GEMM (W2, KLEN=1024) — verified v1 core.
// ---------------------------------------------------------------------------
template <int KLEN>
__global__ __launch_bounds__(512, 2) void mgemm256_sk(const __bf16* __restrict__ A,
                                                      const __bf16* __restrict__ Bt,
                                                      __bf16* __restrict__ P0,
                                                      __bf16* __restrict__ P3,
                                                      int M, int N, int Kstride) {
    int z = blockIdx.z;
    __bf16* C = (z == 3) ? P3 : (P0 + (size_t)z * M * N);
    int tid = threadIdx.x;
    int l = tid & 63, w = tid >> 6;
    int wr = w >> 2, wc = w & 3;
    int m0 = blockIdx.x * 256, n0 = blockIdx.y * 256;
    floatx16 acc[4][2] = {};
    mfma_core256<KLEN>(A, Bt, Kstride, z * KLEN, m0, n0, tid, acc);
#pragma unroll
    for (int i = 0; i < 4; ++i)
#pragma unroll
        for (int j = 0; j < 2; ++j) {
            int col  = n0 + wc * 64 + j * 32 + (l & 31);
            int rowb = m0 + wr * 128 + i * 32 + 4 * (l >> 5);
#pragma unroll
            for (int reg = 0; reg < 16; ++reg) {
                int row = rowb + (reg & 3) + 8 * (reg >> 2);
                C[(size_t)row * N + col] = (__bf16)acc[i][j][reg];
            }
        }
}

// ---------------------------------------------------------------------------
// 256-tile QKV GEMM — verified v1 core. q,k cols to qkv; v cols to Vt.
// ---------------------------------------------------------------------------
__global__ __launch_bounds__(512, 2) void mgemm256_qkv(const __bf16* __restrict__ A,
                                                       const __bf16* __restrict__ Bt,
                                                       __bf16* __restrict__ C,
                                                       __bf16* __restrict__ Vt) {
    const int N = 3072;
    int tid = threadIdx.x;
    int l = tid & 63, w = tid >> 6;
    int wr = w >> 2, wc = w & 3;
    int m0 = blockIdx.x * 256, n0 = blockIdx.y * 256;
    floatx16 acc[4][2] = {};
    mfma_core256<1024>(A, Bt, 1024, 0, m0, n0, tid, acc);
#pragma unroll
    for (int i = 0; i < 4; ++i)
#pragma unroll
        for (int j = 0; j < 2; ++j) {
            int col  = n0 + wc * 64 + j * 32 + (l & 31);
            int rowb = m0 + wr * 128 + i * 32 + 4 * (l >> 5);
            if (col < 2048) {
#pragma unroll
                for (int reg = 0; reg < 16; ++reg) {
                    int row = rowb + (reg & 3) + 8 * (reg >> 2);
                    C[(size_t)row * N + col] = (__bf16)acc[i][j][reg];
                }
            } else {
                int vcol = col - 2048;
                int hh = vcol >> 6, dd = vcol & 63;
#pragma unroll
                for (int rq = 0; rq < 4; rq++) {
                    int row0 = rowb + 8 * rq;
                    int bb = row0 >> 11;
                    int tt = row0 & 2047;
                    bf16x4 pack;
                    pack[0] = (__bf16)acc[i][j][4 * rq + 0];
                    pack[1] = (__bf16)acc[i][j][4 * rq + 1];
                    pack[2] = (__bf16)acc[i][j][4 * rq + 2];
                    pack[3] = (__bf16)acc[i][j][4 * rq + 3];
                    *(bf16x4*)&Vt[(((size_t)bb * 16 + hh) * 64 + dd) * SEQ + tt] = pack;
                }
            }
        }
}

// ---------------------------------------------------------------------------
// MFMA flash attention (verified R5 config, 43.8 us).
// ---------------------------------------------------------------------------
__global__ __launch_bounds__(256) void attn_mfma(const __bf16* __restrict__ qkv,
                                                 const __bf16* __restrict__ Vt,
                                                 __bf16* __restrict__ ctx) {
    __shared__ __bf16 Ks[64 * 64];
    __shared__ __bf16 Vs[64 * 64];
    __shared__ __bf16 Ps[4][16 * 64];
    const int QKVW = 3 * HIDDEN;

    int bh = blockIdx.x;
    int qt = gridDim.y - 1 - blockIdx.y;
    int b = bh >> 4, h = bh & 15;
    int tid = threadIdx.x;
    int lane = tid & 63;
    int w = tid >> 6;
    int m = lane & 15;
    int g = lane >> 4;

    const float QSC = 1.44269504f / 8.0f;
    bf16x8 qf[2];
    {
        const __bf16* Qp = qkv + (size_t)(b * SEQ + qt * 64 + w * 16 + m) * QKVW
                         + h * HDIM + g * 8;
        qf[0] = *(const bf16x8*)(Qp);
        qf[1] = *(const bf16x8*)(Qp + 32);
#pragma unroll
        for (int t = 0; t < 2; t++)
#pragma unroll
            for (int i = 0; i < 8; i++)
                qf[t][i] = (__bf16)((float)qf[t][i] * QSC);
    }

    bf16x8 onesf;
#pragma unroll
    for (int i = 0; i < 8; i++) onesf[i] = (__bf16)1.0f;

    floatx4 oacc[4] = {};
    floatx4 lacc = {};

    int srow = tid >> 2;
    int sc0  = (tid & 3) * 2;
    const __bf16* Kg = qkv + (size_t)(b * SEQ) * QKVW + HIDDEN + h * HDIM;
    const __bf16* Vg = Vt + (size_t)bh * HDIM * SEQ;

    bf16x8 pk0, pk1, pv0, pv1;
    {
        const __bf16* kp = Kg + (size_t)srow * QKVW + sc0 * 8;
        pk0 = *(const bf16x8*)kp;
        pk1 = *(const bf16x8*)(kp + 8);
        const __bf16* vp = Vg + (size_t)srow * SEQ + sc0 * 8;
        pv0 = *(const bf16x8*)vp;
        pv1 = *(const bf16x8*)(vp + 8);
    }

    for (int kt = 0; kt <= qt; kt++) {
        __syncthreads();
        *(bf16x8*)&Ks[srow * 64 + SWZ(srow, sc0)]     = pk0;
        *(bf16x8*)&Ks[srow * 64 + SWZ(srow, sc0 + 1)] = pk1;
        *(bf16x8*)&Vs[srow * 64 + SWZ(srow, sc0)]     = pv0;
        *(bf16x8*)&Vs[srow * 64 + SWZ(srow, sc0 + 1)] = pv1;
        __syncthreads();

        if (kt < qt) {
            const __bf16* kp = Kg + (size_t)((kt + 1) * 64 + srow) * QKVW + sc0 * 8;
            pk0 = *(const bf16x8*)kp;
            pk1 = *(const bf16x8*)(kp + 8);
            const __bf16* vp = Vg + (size_t)srow * SEQ + (kt + 1) * 64 + sc0 * 8;
            pv0 = *(const bf16x8*)vp;
            pv1 = *(const bf16x8*)(vp + 8);
        }

        floatx4 sacc[4] = {};
        __builtin_amdgcn_s_setprio(1);
#pragma unroll
        for (int j = 0; j < 4; j++) {
#pragma unroll
            for (int t = 0; t < 2; t++) {
                int kr = 16 * j + m;
                bf16x8 kf = *(const bf16x8*)&Ks[kr * 64 + SWZ(kr, g + 4 * t)];
                sacc[j] = __builtin_amdgcn_mfma_f32_16x16x32_bf16(
                    qf[t], kf, sacc[j], 0, 0, 0);
            }
        }
        __builtin_amdgcn_s_setprio(0);

        if (kt == qt) {
            int qlocal = w * 16 + 4 * g;
#pragma unroll
            for (int j = 0; j < 4; j++)
#pragma unroll
                for (int r = 0; r < 4; r++)
                    if (16 * j + m > qlocal + r) sacc[j][r] = -INFINITY;
        }

        __bf16* Pw = &Ps[w][0];
#pragma unroll
        for (int j = 0; j < 4; j++)
#pragma unroll
            for (int r = 0; r < 4; r++) {
                float p = exp2f(sacc[j][r]);
                int row = 4 * g + r;
                int key = 16 * j + m;
                Pw[row * 64 + SWZ(row, key >> 3) + (key & 7)] = (__bf16)p;
            }

        __builtin_amdgcn_s_setprio(1);
#pragma unroll
        for (int t = 0; t < 2; t++) {
            bf16x8 pf = *(const bf16x8*)&Pw[m * 64 + SWZ(m, g + 4 * t)];
            lacc = __builtin_amdgcn_mfma_f32_16x16x32_bf16(pf, onesf, lacc, 0, 0, 0);
#pragma unroll
            for (int jd = 0; jd < 4; jd++) {
                int vr = 16 * jd + m;
                bf16x8 vf = *(const bf16x8*)&Vs[vr * 64 + SWZ(vr, g + 4 * t)];
                oacc[jd] = __builtin_amdgcn_mfma_f32_16x16x32_bf16(
                    pf, vf, oacc[jd], 0, 0, 0);
            }
        }
        __builtin_amdgcn_s_setprio(0);
    }

#pragma unroll
    for (int r = 0; r < 4; r++) {
        float invl = 1.0f / lacc[r];
        int row = qt * 64 + w * 16 + 4 * g + r;
        __bf16* cp = ctx + (size_t)(b * SEQ + row) * HIDDEN + h * HDIM;
#pragma unroll
        for (int jd = 0; jd < 4; jd++)
            cp[16 * jd + m] = (__bf16)(oacc[jd][r] * invl);
    }
}

// ---------------------------------------------------------------------------
extern "C" void kernel_launch(void* const* d_in, const int* in_sizes, int n_in,
                              void* d_out, int out_size, void* d_ws, size_t ws_size,
                              hipStream_t stream) {
    (void)in_sizes; (void)n_in; (void)out_size; (void)ws_size;
    const float* emb = (const float*)d_in[0];
    const float* Wq  = (const float*)d_in[1];
    const float* Wk  = (const float*)d_in[2];
    const float* Wv  = (const float*)d_in[3];
    const float* Wo  = (const float*)d_in[4];
    const float* W1  = (const float*)d_in[5];
    const float* b1  = (const float*)d_in[6];
    const float* W2  = (const float*)d_in[7];
    const float* b2  = (const float*)d_in[8];
    const float* g1  = (const float*)d_in[9];
    const float* be1 = (const float*)d_in[10];
    const float* g2  = (const float*)d_in[11];
    const float* be2 = (const float*)d_in[12];
    float* out = (float*)d_out;

    // ws layout (bf16 elems; ME = 1M elems = 2MB). Total 36 ME = 72 MB.
    __bf16* wsb = (__bf16*)d_ws;
    const size_t ME = 1024 * 1024;
    __bf16* h     = wsb;
    __bf16* qkv   = wsb + 4 * ME;
    __bf16* ctx   = wsb;
    __bf16* ff1   = wsb;
    __bf16* h2    = wsb + 16 * ME;
    __bf16* BtQKV = wsb + 20 * ME;
    __bf16* BtO   = wsb + 23 * ME;
    __bf16* Bt1   = wsb + 24 * ME;
    __bf16* Bt2   = wsb + 28 * ME;
    __bf16* Vt    = wsb + 32 * ME;
    __bf16* woP   = wsb + 4 * ME;    // 2 x 4 ME
    __bf16* w2P0  = wsb + 16 * ME;   // z0..z2 contiguous (12 ME)
    __bf16* w2P3  = wsb + 32 * ME;   // z3

    prep_all<<<16384, 256, 0, stream>>>(Wq, Wk, Wv, Wo, W1, W2,
                                        BtQKV, BtO, Bt1, Bt2,
                                        emb, g1, be1, h);

    mgemm256_qkv<<<dim3(16, 12), 512, 0, stream>>>(h, BtQKV, qkv, Vt);

    attn_mfma<<<dim3(32, 32), 256, 0, stream>>>(qkv, Vt, ctx);

    // Wo split-K x2 on the legacy 128-tile core, bf16 partials
    mgemm_sk<<<dim3(32, 8, 2), 256, 0, stream>>>(
        ctx, BtO, woP, nullptr, ROWS, 1024, 1024, 512);
    red_wo_ln<<<ROWS, 256, 0, stream>>>(emb, woP, woP + 4 * ME, g2, be2, out, h2);

    mgemm256<true, true><<<dim3(16, 16), 512, 0, stream>>>(
        h2, Bt1, b1, ff1, 4096, 1024);

    // W2 split-K x4 on the 256-tile core, bf16 partials
    mgemm256_sk<1024><<<dim3(16, 4, 4), 512, 0, stream>>>(
        ff1, Bt2, w2P0, w2P3, ROWS, 1024, 4096);
    red_w2<<<2048, 256, 0, stream>>>(w2P0, w2P3, b2, out, 1024);
}

// Round 12
// 300.725 us; speedup vs baseline: 1.0496x; 1.0239x over previous
//
#include <hip/hip_runtime.h>
#include <math.h>

#define HIDDEN 1024
#define SEQ    2048
#define NHEAD  16
#define HDIM   64
#define ROWS   (2 * SEQ)

typedef float  floatx4  __attribute__((ext_vector_type(4)));
typedef float  floatx16 __attribute__((ext_vector_type(16)));
typedef __bf16 bf16x8   __attribute__((ext_vector_type(8)));
typedef __bf16 bf16x4   __attribute__((ext_vector_type(4)));

#define AS1(p) ((const __attribute__((address_space(1))) void*)(p))
#define AS3(p) ((__attribute__((address_space(3))) void*)(p))

// swizzled byte-chunk offset (in elements): 16B chunks XOR'd by row&7 (attn)
#define SWZ(row, chunk) ((((chunk) ^ ((row) & 7)) * 8))

// [R7: XCD swizzle regressed. R8: STG-before-reads regressed. R9: wall noise
//  ±10us. R10: "container failed" = infra flake (R11 ran the same core fine).
//  R11: 4-phase core validated on W1 (pass, W1 <= 43.6us). R12: full port.]

// ---------------------------------------------------------------------------
// Prep launch: 6 weight converts + LayerNorm1, one kernel.
// ---------------------------------------------------------------------------
__global__ __launch_bounds__(256) void prep_all(const float* __restrict__ Wq,
                                                const float* __restrict__ Wk,
                                                const float* __restrict__ Wv,
                                                const float* __restrict__ Wo,
                                                const float* __restrict__ W1,
                                                const float* __restrict__ W2,
                                                __bf16* __restrict__ BtQKV,
                                                __bf16* __restrict__ BtO,
                                                __bf16* __restrict__ Bt1,
                                                __bf16* __restrict__ Bt2,
                                                const float* __restrict__ emb,
                                                const float* __restrict__ g1,
                                                const float* __restrict__ be1,
                                                __bf16* __restrict__ h) {
    int id = blockIdx.x;
    int tid = threadIdx.x;
    if (id >= 12288) {
        // ---- LayerNorm1 row ----
        int row = id - 12288;
        size_t i = (size_t)row * HIDDEN + tid * 4;
        float4 v = *(const float4*)(emb + i);
        float s  = v.x + v.y + v.z + v.w;
        float s2 = v.x * v.x + v.y * v.y + v.z * v.z + v.w * v.w;
#pragma unroll
        for (int off = 1; off < 64; off <<= 1) {
            s  += __shfl_xor(s, off, 64);
            s2 += __shfl_xor(s2, off, 64);
        }
        __shared__ float red[8];
        int wid = tid >> 6;
        if ((tid & 63) == 0) { red[wid] = s; red[wid + 4] = s2; }
        __syncthreads();
        s  = red[0] + red[1] + red[2] + red[3];
        s2 = red[4] + red[5] + red[6] + red[7];
        float mu  = s * (1.0f / HIDDEN);
        float var = fmaxf(s2 * (1.0f / HIDDEN) - mu * mu, 0.0f);
        float inv = rsqrtf(var + 1e-5f);
        float4 gv = *(const float4*)(g1 + tid * 4);
        float4 bv = *(const float4*)(be1 + tid * 4);
        bf16x4 o;
        o[0] = (__bf16)((v.x - mu) * inv * gv.x + bv.x);
        o[1] = (__bf16)((v.y - mu) * inv * gv.y + bv.y);
        o[2] = (__bf16)((v.z - mu) * inv * gv.z + bv.z);
        o[3] = (__bf16)((v.w - mu) * inv * gv.w + bv.w);
        *(bf16x4*)(h + i) = o;
        return;
    }
    // ---- weight convert tile (32x32) ----
    __shared__ float t[32][33];
    const float* in; __bf16* out; int K, N, nt, kt;
    if (id < 4096) {
        int job = id >> 10, tt = id & 1023;
        nt = tt & 31; kt = tt >> 5; K = 1024; N = 1024;
        if (job == 0)      { in = Wq; out = BtQKV; }
        else if (job == 1) { in = Wk; out = BtQKV + 1024 * 1024; }
        else if (job == 2) { in = Wv; out = BtQKV + 2 * 1024 * 1024; }
        else               { in = Wo; out = BtO; }
    } else if (id < 8192) {
        int tt = id - 4096;
        nt = tt & 127; kt = tt >> 7; K = 1024; N = 4096; in = W1; out = Bt1;
    } else {
        int tt = id - 8192;
        nt = tt & 31; kt = tt >> 5; K = 4096; N = 1024; in = W2; out = Bt2;
    }
    bool frag = (id >= 3072 && id < 4096);    // only Wo keeps fragment-major
    int n0 = nt * 32, k0 = kt * 32;
    int r  = tid >> 3;             // n within tile
    int c4 = (tid & 7) * 4;        // k run of 4
    float4 v = *(const float4*)(in + (size_t)(k0 + r) * N + n0 + c4);
    t[r][c4 + 0] = v.x; t[r][c4 + 1] = v.y; t[r][c4 + 2] = v.z; t[r][c4 + 3] = v.w;
    __syncthreads();
    bf16x4 o;
    o[0] = (__bf16)t[c4 + 0][r];
    o[1] = (__bf16)t[c4 + 1][r];
    o[2] = (__bf16)t[c4 + 2][r];
    o[3] = (__bf16)t[c4 + 3][r];
    int n = n0 + r, k = k0 + c4;
    if (!frag) {
        *(bf16x4*)(out + (size_t)n * K + k) = o;
    } else {
        size_t blk = (size_t)(n >> 5) * (K >> 4) + (k >> 4);
        int ln = ((k >> 3) & 1) * 32 + (n & 31);
        *(bf16x4*)(out + blk * 512 + ln * 8 + (k & 7)) = o;
    }
}

// ---------------------------------------------------------------------------
// Fused Wo-split-K(x2) reduction + residual + LayerNorm2.
// ---------------------------------------------------------------------------
__global__ __launch_bounds__(256) void red_wo_ln(const float* __restrict__ emb,
                                                 const __bf16* __restrict__ p0,
                                                 const __bf16* __restrict__ p1,
                                                 const float* __restrict__ g,
                                                 const float* __restrict__ beta,
                                                 float* __restrict__ out,
                                                 __bf16* __restrict__ h2) {
    int row = blockIdx.x;
    int tid = threadIdx.x;
    size_t i = (size_t)row * HIDDEN + tid * 4;
    float4 e = *(const float4*)(emb + i);
    bf16x4 a = *(const bf16x4*)(p0 + i);
    bf16x4 b = *(const bf16x4*)(p1 + i);
    float4 v;
    v.x = e.x + (float)a[0] + (float)b[0];
    v.y = e.y + (float)a[1] + (float)b[1];
    v.z = e.z + (float)a[2] + (float)b[2];
    v.w = e.w + (float)a[3] + (float)b[3];
    *(float4*)(out + i) = v;

    float s  = v.x + v.y + v.z + v.w;
    float s2 = v.x * v.x + v.y * v.y + v.z * v.z + v.w * v.w;
#pragma unroll
    for (int off = 1; off < 64; off <<= 1) {
        s  += __shfl_xor(s, off, 64);
        s2 += __shfl_xor(s2, off, 64);
    }
    __shared__ float red[8];
    int wid = tid >> 6;
    if ((tid & 63) == 0) { red[wid] = s; red[wid + 4] = s2; }
    __syncthreads();
    s  = red[0] + red[1] + red[2] + red[3];
    s2 = red[4] + red[5] + red[6] + red[7];
    float mu  = s * (1.0f / HIDDEN);
    float var = fmaxf(s2 * (1.0f / HIDDEN) - mu * mu, 0.0f);
    float inv = rsqrtf(var + 1e-5f);
    float4 gv = *(const float4*)(g + tid * 4);
    float4 bv = *(const float4*)(beta + tid * 4);
    bf16x4 o;
    o[0] = (__bf16)((v.x - mu) * inv * gv.x + bv.x);
    o[1] = (__bf16)((v.y - mu) * inv * gv.y + bv.y);
    o[2] = (__bf16)((v.z - mu) * inv * gv.z + bv.z);
    o[3] = (__bf16)((v.w - mu) * inv * gv.w + bv.w);
    *(bf16x4*)(h2 + i) = o;
}

// ---------------------------------------------------------------------------
// W2 reduction: out += p0+p1+p2+p3 + b2[col]
// ---------------------------------------------------------------------------
__global__ __launch_bounds__(256) void red_w2(const __bf16* __restrict__ p0,
                                              const __bf16* __restrict__ p3,
                                              const float* __restrict__ b2,
                                              float* __restrict__ out,
                                              int N) {
    size_t i = ((size_t)blockIdx.x * 256 + threadIdx.x) * 8;
    const size_t MN = (size_t)ROWS * HIDDEN;
    bf16x8 a = *(const bf16x8*)(p0 + i);
    bf16x8 b = *(const bf16x8*)(p0 + MN + i);
    bf16x8 c = *(const bf16x8*)(p0 + 2 * MN + i);
    bf16x8 d = *(const bf16x8*)(p3 + i);
    int col = (int)(i & (size_t)(N - 1));
    float4 bb0 = *(const float4*)(b2 + col);
    float4 bb1 = *(const float4*)(b2 + col + 4);
    float4 o0 = *(const float4*)(out + i);
    float4 o1 = *(const float4*)(out + i + 4);
    o0.x += (float)a[0] + (float)b[0] + (float)c[0] + (float)d[0] + bb0.x;
    o0.y += (float)a[1] + (float)b[1] + (float)c[1] + (float)d[1] + bb0.y;
    o0.z += (float)a[2] + (float)b[2] + (float)c[2] + (float)d[2] + bb0.z;
    o0.w += (float)a[3] + (float)b[3] + (float)c[3] + (float)d[3] + bb0.w;
    o1.x += (float)a[4] + (float)b[4] + (float)c[4] + (float)d[4] + bb1.x;
    o1.y += (float)a[5] + (float)b[5] + (float)c[5] + (float)d[5] + bb1.y;
    o1.z += (float)a[6] + (float)b[6] + (float)c[6] + (float)d[6] + bb1.z;
    o1.w += (float)a[7] + (float)b[7] + (float)c[7] + (float)d[7] + bb1.w;
    *(float4*)(out + i)     = o0;
    *(float4*)(out + i + 4) = o1;
}

// ---------------------------------------------------------------------------
// Legacy 128x128 MFMA core (Wo split-K only — short-K regime winner).
// ---------------------------------------------------------------------------
__device__ __forceinline__ void mfma_core128(const __bf16* __restrict__ A,
                                             const __bf16* __restrict__ BtF,
                                             int Kstride, int kbase, int Klen,
                                             int m0, int n0, int tid,
                                             floatx16 (&acc)[2][2]) {
    __shared__ __bf16 As[2 * 128 * 32];
    const int BUF = 128 * 32;
    int lane = tid & 63;
    int wave = tid >> 6;
    int wr = wave >> 1, wc = wave & 1;

    int sr = lane >> 2;
    int sk = 8 * ((lane & 3) ^ ((sr >> 1) & 3));
    const __bf16* ga0 = A + (size_t)(m0 + wave * 16 + sr) * Kstride + kbase + sk;
    const __bf16* ga1 = ga0 + (size_t)64 * Kstride;
    __bf16* la0 = &As[wave * 512];
    __bf16* la1 = &As[2048 + wave * 512];

    int fm = lane & 31;
    int gswz = (lane >> 1) & 3;
    int slot0 = ((lane >> 5) + 0) ^ gswz;
    int slot1 = ((lane >> 5) + 2) ^ gswz;

    const __bf16* bb = BtF + ((size_t)((n0 >> 5) + wc * 2) * (Kstride >> 4)) * 512
                     + (size_t)lane * 8;
    const size_t jstr = (size_t)(Kstride >> 4) * 512;
    int ci0 = kbase >> 4;

    __builtin_amdgcn_global_load_lds(AS1(ga0), AS3(la0), 16, 0, 0);
    __builtin_amdgcn_global_load_lds(AS1(ga1), AS3(la1), 16, 0, 0);
    bf16x8 bcur[2][2], bnxt[2][2];
#pragma unroll
    for (int j = 0; j < 2; j++)
#pragma unroll
        for (int t = 0; t < 2; t++)
            bcur[j][t] = *(const bf16x8*)(bb + j * jstr + (size_t)(ci0 + t) * 512);

    int buf = 0;
    for (int k0 = 0; k0 < Klen; k0 += 32, buf ^= 1) {
        __syncthreads();
        if (k0 + 32 < Klen) {
            int nb = (buf ^ 1) * BUF;
            __builtin_amdgcn_global_load_lds(AS1(ga0 + k0 + 32), AS3(la0 + nb), 16, 0, 0);
            __builtin_amdgcn_global_load_lds(AS1(ga1 + k0 + 32), AS3(la1 + nb), 16, 0, 0);
            int ci = ci0 + ((k0 + 32) >> 4);
#pragma unroll
            for (int j = 0; j < 2; j++)
#pragma unroll
                for (int t = 0; t < 2; t++)
                    bnxt[j][t] = *(const bf16x8*)(bb + j * jstr + (size_t)(ci + t) * 512);
        }
        const __bf16* Ab = As + buf * BUF;
        bf16x8 af[2][2];
#pragma unroll
        for (int i = 0; i < 2; i++) {
            const __bf16* rp = Ab + (size_t)(wr * 64 + i * 32 + fm) * 32;
            af[i][0] = *(const bf16x8*)(rp + slot0 * 8);
            af[i][1] = *(const bf16x8*)(rp + slot1 * 8);
        }
#pragma unroll
        for (int t = 0; t < 2; t++)
#pragma unroll
            for (int i = 0; i < 2; i++)
#pragma unroll
                for (int j = 0; j < 2; j++)
                    acc[i][j] = __builtin_amdgcn_mfma_f32_32x32x16_bf16(
                        af[i][t], bcur[j][t], acc[i][j], 0, 0, 0);
#pragma unroll
        for (int j = 0; j < 2; j++)
#pragma unroll
            for (int t = 0; t < 2; t++)
                bcur[j][t] = bnxt[j][t];
    }
}

// ---------------------------------------------------------------------------
// Split-K GEMM on the legacy core (Wo only; z in {0,1}).
// ---------------------------------------------------------------------------
__global__ __launch_bounds__(256) void mgemm_sk(const __bf16* __restrict__ A,
                                                const __bf16* __restrict__ BtF,
                                                __bf16* __restrict__ P0,
                                                __bf16* __restrict__ P3,
                                                int M, int N, int Kstride, int Klen) {
    int z = blockIdx.z;
    __bf16* C = (z == 3) ? P3 : (P0 + (size_t)z * M * N);
    int tid = threadIdx.x;
    int lane = tid & 63;
    int wave = tid >> 6;
    int m0 = blockIdx.x * 128, n0 = blockIdx.y * 128;
    int wr = wave >> 1, wc = wave & 1;
    floatx16 acc[2][2] = {};
    mfma_core128(A, BtF, Kstride, z * Klen, Klen, m0, n0, tid, acc);

#pragma unroll
    for (int i = 0; i < 2; i++) {
#pragma unroll
        for (int j = 0; j < 2; j++) {
            int col  = n0 + wc * 64 + j * 32 + (lane & 31);
            int rowb = m0 + wr * 64 + i * 32 + 4 * (lane >> 5);
#pragma unroll
            for (int reg = 0; reg < 16; reg++) {
                int row = rowb + (reg & 3) + 8 * (reg >> 2);
                C[(size_t)row * N + col] = (__bf16)acc[i][j][reg];
            }
        }
    }
}

// ---------------------------------------------------------------------------
// 256x256 MFMA core v2 — 4-phase derived-waits (validated on W1, R11).
// 512 thr = 8 waves (2M x 4N); K-step 64; ring-2 (128 KiB).
// Ledger: 2 loads/wave/phase uniform; ph0 vmcnt(3), ph1 4|2, ph2 5|1, ph3 6|0.
// ---------------------------------------------------------------------------
template <int KLEN>
__device__ __forceinline__ void mfma_core256p4(const __bf16* __restrict__ A,
                                               const __bf16* __restrict__ Bt,
                                               int Kstride, int kbase,
                                               int m0, int n0, int tid,
                                               floatx16 (&acc)[4][2]) {
    __shared__ __bf16 lds[65536];             // 128 KiB
    const int NS = KLEN >> 6;                 // K-steps of 64 (NS >= 2)
    int l = tid & 63;
    int w = tid >> 6;
    int wr = w >> 2, wc = w & 3;

    int srg = l >> 3;                          // row within 8-row group (0..7)
    int scf = ((l & 7) ^ srg) * 8;             // swizzled chunk offset (elems)
    const __bf16* gB = Bt + (size_t)(n0 + w * 16 + srg) * Kstride + kbase + scf;
    const __bf16* gA = A  + (size_t)(m0 + wr * 128 + (w & 3) * 8 + srg) * Kstride
                     + kbase + scf;
    __bf16* lBd = lds + 32768 + (w * 16) * 64 + l * 8;
    __bf16* lAd = lds + wr * 2048 + (w & 3) * 512 + l * 8;

#define STG_BH(tb, hb, kk) do {                                                          \
    __builtin_amdgcn_global_load_lds(AS1(gB + (size_t)(hb) * 128 * Kstride + (kk)),      \
                                     AS3(lBd + (tb) * 16384 + (hb) * 8192), 16, 0, 0);   \
    __builtin_amdgcn_global_load_lds(AS1(gB + (size_t)((hb) * 128 + 8) * Kstride + (kk)),\
                                     AS3(lBd + (tb) * 16384 + (hb) * 8192 + 512), 16, 0, 0); } while (0)
#define STG_AQ(tb, q, kk)                                                                \
    __builtin_amdgcn_global_load_lds(AS1(gA + (size_t)(q) * 32 * Kstride + (kk)),        \
                                     AS3(lAd + (tb) * 16384 + (q) * 4096), 16, 0, 0)

    int fm = l & 31, cc = l >> 5;
    int pc[4];
#pragma unroll
    for (int u = 0; u < 4; ++u) pc[u] = ((2 * u + cc) ^ (fm & 7)) * 8;
    int aOff = wr * 2048 + fm * 64;
    int bOff = 32768 + ((wc & 1) * 64 + fm) * 64 + (wc >> 1) * 8192;

    STG_BH(0, 0, 0); STG_BH(0, 1, 0);
    STG_AQ(0, 0, 0); STG_AQ(0, 1, 0); STG_AQ(0, 2, 0); STG_AQ(0, 3, 0);

    for (int S = 0; S < NS; ++S) {
        int b = S & 1, tb = b ^ 1;
        int kk = (S + 1) * 64;
        bool pf = (S + 1) < NS;
        const __bf16* aB_ = lds + b * 16384 + aOff;
        const __bf16* bB_ = lds + b * 16384 + bOff;

        bf16x8 bc[2][4];
        // ---- phase 0: acc[0][*] ----
        asm volatile("s_waitcnt vmcnt(3)\n\ts_barrier" ::: "memory");
        {
            bf16x8 a[4];
#pragma unroll
            for (int j = 0; j < 2; ++j)
#pragma unroll
                for (int u = 0; u < 4; ++u)
                    bc[j][u] = *(const bf16x8*)(bB_ + j * 2048 + pc[u]);
#pragma unroll
            for (int u = 0; u < 4; ++u)
                a[u] = *(const bf16x8*)(aB_ + 0 * 4096 + pc[u]);
            if (pf) STG_BH(tb, 0, kk);
            asm volatile("s_waitcnt lgkmcnt(0)" ::: "memory");
            __builtin_amdgcn_sched_barrier(0);
            __builtin_amdgcn_s_setprio(1);
#pragma unroll
            for (int u = 0; u < 4; ++u)
#pragma unroll
                for (int j = 0; j < 2; ++j)
                    acc[0][j] = __builtin_amdgcn_mfma_f32_32x32x16_bf16(
                        a[u], bc[j][u], acc[0][j], 0, 0, 0);
            __builtin_amdgcn_s_setprio(0);
        }
        // ---- phase 1: acc[1][*] ----
        if (pf) asm volatile("s_waitcnt vmcnt(4)\n\ts_barrier" ::: "memory");
        else    asm volatile("s_waitcnt vmcnt(2)\n\ts_barrier" ::: "memory");
        {
            bf16x8 a[4];
#pragma unroll
            for (int u = 0; u < 4; ++u)
                a[u] = *(const bf16x8*)(aB_ + 1 * 4096 + pc[u]);
            if (pf) STG_BH(tb, 1, kk);
            asm volatile("s_waitcnt lgkmcnt(0)" ::: "memory");
            __builtin_amdgcn_sched_barrier(0);
            __builtin_amdgcn_s_setprio(1);
#pragma unroll
            for (int u = 0; u < 4; ++u)
#pragma unroll
                for (int j = 0; j < 2; ++j)
                    acc[1][j] = __builtin_amdgcn_mfma_f32_32x32x16_bf16(
                        a[u], bc[j][u], acc[1][j], 0, 0, 0);
            __builtin_amdgcn_s_setprio(0);
        }
        // ---- phase 2: acc[2][*] ----
        if (pf) asm volatile("s_waitcnt vmcnt(5)\n\ts_barrier" ::: "memory");
        else    asm volatile("s_waitcnt vmcnt(1)\n\ts_barrier" ::: "memory");
        {
            bf16x8 a[4];
#pragma unroll
            for (int u = 0; u < 4; ++u)
                a[u] = *(const bf16x8*)(aB_ + 2 * 4096 + pc[u]);
            if (pf) { STG_AQ(tb, 0, kk); STG_AQ(tb, 1, kk); }
            asm volatile("s_waitcnt lgkmcnt(0)" ::: "memory");
            __builtin_amdgcn_sched_barrier(0);
            __builtin_amdgcn_s_setprio(1);
#pragma unroll
            for (int u = 0; u < 4; ++u)
#pragma unroll
                for (int j = 0; j < 2; ++j)
                    acc[2][j] = __builtin_amdgcn_mfma_f32_32x32x16_bf16(
                        a[u], bc[j][u], acc[2][j], 0, 0, 0);
            __builtin_amdgcn_s_setprio(0);
        }
        // ---- phase 3: acc[3][*] ----
        if (pf) asm volatile("s_waitcnt vmcnt(6)\n\ts_barrier" ::: "memory");
        else    asm volatile("s_waitcnt vmcnt(0)\n\ts_barrier" ::: "memory");
        {
            bf16x8 a[4];
#pragma unroll
            for (int u = 0; u < 4; ++u)
                a[u] = *(const bf16x8*)(aB_ + 3 * 4096 + pc[u]);
            if (pf) { STG_AQ(tb, 2, kk); STG_AQ(tb, 3, kk); }
            asm volatile("s_waitcnt lgkmcnt(0)" ::: "memory");
            __builtin_amdgcn_sched_barrier(0);
            __builtin_amdgcn_s_setprio(1);
#pragma unroll
            for (int u = 0; u < 4; ++u)
#pragma unroll
                for (int j = 0; j < 2; ++j)
                    acc[3][j] = __builtin_amdgcn_mfma_f32_32x32x16_bf16(
                        a[u], bc[j][u], acc[3][j], 0, 0, 0);
            __builtin_amdgcn_s_setprio(0);
        }
    }
#undef STG_BH
#undef STG_AQ
}

// ---------------------------------------------------------------------------
// 256-tile GEMM with bias/ReLU epilogue (W1) — v2 4-phase core.
// ---------------------------------------------------------------------------
template <bool BIAS, bool RELU>
__global__ __launch_bounds__(512, 2) void mgemm256(const __bf16* __restrict__ A,
                                                   const __bf16* __restrict__ Bt,
                                                   const float* __restrict__ bias,
                                                   __bf16* __restrict__ C,
                                                   int N, int Kstride) {
    int tid = threadIdx.x;
    int l = tid & 63, w = tid >> 6;
    int wr = w >> 2, wc = w & 3;
    int m0 = blockIdx.x * 256, n0 = blockIdx.y * 256;
    floatx16 acc[4][2] = {};
    mfma_core256p4<1024>(A, Bt, Kstride, 0, m0, n0, tid, acc);
#pragma unroll
    for (int i = 0; i < 4; ++i)
#pragma unroll
        for (int j = 0; j < 2; ++j) {
            int col  = n0 + wc * 64 + j * 32 + (l & 31);
            int rowb = m0 + wr * 128 + i * 32 + 4 * (l >> 5);
            float bv = 0.0f;
            if (BIAS) bv = bias[col];
#pragma unroll
            for (int reg = 0; reg < 16; ++reg) {
                int row = rowb + (reg & 3) + 8 * (reg >> 2);
                float v = acc[i][j][reg] + bv;
                if (RELU) v = fmaxf(v, 0.0f);
                C[(size_t)row * N + col] = (__bf16)v;
            }
        }
}

// ---------------------------------------------------------------------------
// 256-tile split-K GEMM (W2, KLEN=1024) — v2 4-phase core.
// ---------------------------------------------------------------------------
template <int KLEN>
__global__ __launch_bounds__(512, 2) void mgemm256_sk(const __bf16* __restrict__ A,
                                                      const __bf16* __restrict__ Bt,
                                                      __bf16* __restrict__ P0,
                                                      __bf16* __restrict__ P3,
                                                      int M, int N, int Kstride) {
    int z = blockIdx.z;
    __bf16* C = (z == 3) ? P3 : (P0 + (size_t)z * M * N);
    int tid = threadIdx.x;
    int l = tid & 63, w = tid >> 6;
    int wr = w >> 2, wc = w & 3;
    int m0 = blockIdx.x * 256, n0 = blockIdx.y * 256;
    floatx16 acc[4][2] = {};
    mfma_core256p4<KLEN>(A, Bt, Kstride, z * KLEN, m0, n0, tid, acc);
#pragma unroll
    for (int i = 0; i < 4; ++i)
#pragma unroll
        for (int j = 0; j < 2; ++j) {
            int col  = n0 + wc * 64 + j * 32 + (l & 31);
            int rowb = m0 + wr * 128 + i * 32 + 4 * (l >> 5);
#pragma unroll
            for (int reg = 0; reg < 16; ++reg) {
                int row = rowb + (reg & 3) + 8 * (reg >> 2);
                C[(size_t)row * N + col] = (__bf16)acc[i][j][reg];
            }
        }
}

// ---------------------------------------------------------------------------
// 256-tile QKV GEMM — v2 4-phase core. q,k cols to qkv; v cols to Vt.
// ---------------------------------------------------------------------------
__global__ __launch_bounds__(512, 2) void mgemm256_qkv(const __bf16* __restrict__ A,
                                                       const __bf16* __restrict__ Bt,
                                                       __bf16* __restrict__ C,
                                                       __bf16* __restrict__ Vt) {
    const int N = 3072;
    int tid = threadIdx.x;
    int l = tid & 63, w = tid >> 6;
    int wr = w >> 2, wc = w & 3;
    int m0 = blockIdx.x * 256, n0 = blockIdx.y * 256;
    floatx16 acc[4][2] = {};
    mfma_core256p4<1024>(A, Bt, 1024, 0, m0, n0, tid, acc);
#pragma unroll
    for (int i = 0; i < 4; ++i)
#pragma unroll
        for (int j = 0; j < 2; ++j) {
            int col  = n0 + wc * 64 + j * 32 + (l & 31);
            int rowb = m0 + wr * 128 + i * 32 + 4 * (l >> 5);
            if (col < 2048) {
#pragma unroll
                for (int reg = 0; reg < 16; ++reg) {
                    int row = rowb + (reg & 3) + 8 * (reg >> 2);
                    C[(size_t)row * N + col] = (__bf16)acc[i][j][reg];
                }
            } else {
                int vcol = col - 2048;
                int hh = vcol >> 6, dd = vcol & 63;
#pragma unroll
                for (int rq = 0; rq < 4; rq++) {
                    int row0 = rowb + 8 * rq;
                    int bb = row0 >> 11;
                    int tt = row0 & 2047;
                    bf16x4 pack;
                    pack[0] = (__bf16)acc[i][j][4 * rq + 0];
                    pack[1] = (__bf16)acc[i][j][4 * rq + 1];
                    pack[2] = (__bf16)acc[i][j][4 * rq + 2];
                    pack[3] = (__bf16)acc[i][j][4 * rq + 3];
                    *(bf16x4*)&Vt[(((size_t)bb * 16 + hh) * 64 + dd) * SEQ + tt] = pack;
                }
            }
        }
}

// ---------------------------------------------------------------------------
// MFMA flash attention (verified R5 config, 43.8 us).
// ---------------------------------------------------------------------------
__global__ __launch_bounds__(256) void attn_mfma(const __bf16* __restrict__ qkv,
                                                 const __bf16* __restrict__ Vt,
                                                 __bf16* __restrict__ ctx) {
    __shared__ __bf16 Ks[64 * 64];
    __shared__ __bf16 Vs[64 * 64];
    __shared__ __bf16 Ps[4][16 * 64];
    const int QKVW = 3 * HIDDEN;

    int bh = blockIdx.x;
    int qt = gridDim.y - 1 - blockIdx.y;
    int b = bh >> 4, h = bh & 15;
    int tid = threadIdx.x;
    int lane = tid & 63;
    int w = tid >> 6;
    int m = lane & 15;
    int g = lane >> 4;

    const float QSC = 1.44269504f / 8.0f;
    bf16x8 qf[2];
    {
        const __bf16* Qp = qkv + (size_t)(b * SEQ + qt * 64 + w * 16 + m) * QKVW
                         + h * HDIM + g * 8;
        qf[0] = *(const bf16x8*)(Qp);
        qf[1] = *(const bf16x8*)(Qp + 32);
#pragma unroll
        for (int t = 0; t < 2; t++)
#pragma unroll
            for (int i = 0; i < 8; i++)
                qf[t][i] = (__bf16)((float)qf[t][i] * QSC);
    }

    bf16x8 onesf;
#pragma unroll
    for (int i = 0; i < 8; i++) onesf[i] = (__bf16)1.0f;

    floatx4 oacc[4] = {};
    floatx4 lacc = {};

    int srow = tid >> 2;
    int sc0  = (tid & 3) * 2;
    const __bf16* Kg = qkv + (size_t)(b * SEQ) * QKVW + HIDDEN + h * HDIM;
    const __bf16* Vg = Vt + (size_t)bh * HDIM * SEQ;

    bf16x8 pk0, pk1, pv0, pv1;
    {
        const __bf16* kp = Kg + (size_t)srow * QKVW + sc0 * 8;
        pk0 = *(const bf16x8*)kp;
        pk1 = *(const bf16x8*)(kp + 8);
        const __bf16* vp = Vg + (size_t)srow * SEQ + sc0 * 8;
        pv0 = *(const bf16x8*)vp;
        pv1 = *(const bf16x8*)(vp + 8);
    }

    for (int kt = 0; kt <= qt; kt++) {
        __syncthreads();
        *(bf16x8*)&Ks[srow * 64 + SWZ(srow, sc0)]     = pk0;
        *(bf16x8*)&Ks[srow * 64 + SWZ(srow, sc0 + 1)] = pk1;
        *(bf16x8*)&Vs[srow * 64 + SWZ(srow, sc0)]     = pv0;
        *(bf16x8*)&Vs[srow * 64 + SWZ(srow, sc0 + 1)] = pv1;
        __syncthreads();

        if (kt < qt) {
            const __bf16* kp = Kg + (size_t)((kt + 1) * 64 + srow) * QKVW + sc0 * 8;
            pk0 = *(const bf16x8*)kp;
            pk1 = *(const bf16x8*)(kp + 8);
            const __bf16* vp = Vg + (size_t)srow * SEQ + (kt + 1) * 64 + sc0 * 8;
            pv0 = *(const bf16x8*)vp;
            pv1 = *(const bf16x8*)(vp + 8);
        }

        floatx4 sacc[4] = {};
        __builtin_amdgcn_s_setprio(1);
#pragma unroll
        for (int j = 0; j < 4; j++) {
#pragma unroll
            for (int t = 0; t < 2; t++) {
                int kr = 16 * j + m;
                bf16x8 kf = *(const bf16x8*)&Ks[kr * 64 + SWZ(kr, g + 4 * t)];
                sacc[j] = __builtin_amdgcn_mfma_f32_16x16x32_bf16(
                    qf[t], kf, sacc[j], 0, 0, 0);
            }
        }
        __builtin_amdgcn_s_setprio(0);

        if (kt == qt) {
            int qlocal = w * 16 + 4 * g;
#pragma unroll
            for (int j = 0; j < 4; j++)
#pragma unroll
                for (int r = 0; r < 4; r++)
                    if (16 * j + m > qlocal + r) sacc[j][r] = -INFINITY;
        }

        __bf16* Pw = &Ps[w][0];
#pragma unroll
        for (int j = 0; j < 4; j++)
#pragma unroll
            for (int r = 0; r < 4; r++) {
                float p = exp2f(sacc[j][r]);
                int row = 4 * g + r;
                int key = 16 * j + m;
                Pw[row * 64 + SWZ(row, key >> 3) + (key & 7)] = (__bf16)p;
            }

        __builtin_amdgcn_s_setprio(1);
#pragma unroll
        for (int t = 0; t < 2; t++) {
            bf16x8 pf = *(const bf16x8*)&Pw[m * 64 + SWZ(m, g + 4 * t)];
            lacc = __builtin_amdgcn_mfma_f32_16x16x32_bf16(pf, onesf, lacc, 0, 0, 0);
#pragma unroll
            for (int jd = 0; jd < 4; jd++) {
                int vr = 16 * jd + m;
                bf16x8 vf = *(const bf16x8*)&Vs[vr * 64 + SWZ(vr, g + 4 * t)];
                oacc[jd] = __builtin_amdgcn_mfma_f32_16x16x32_bf16(
                    pf, vf, oacc[jd], 0, 0, 0);
            }
        }
        __builtin_amdgcn_s_setprio(0);
    }

#pragma unroll
    for (int r = 0; r < 4; r++) {
        float invl = 1.0f / lacc[r];
        int row = qt * 64 + w * 16 + 4 * g + r;
        __bf16* cp = ctx + (size_t)(b * SEQ + row) * HIDDEN + h * HDIM;
#pragma unroll
        for (int jd = 0; jd < 4; jd++)
            cp[16 * jd + m] = (__bf16)(oacc[jd][r] * invl);
    }
}

// ---------------------------------------------------------------------------
extern "C" void kernel_launch(void* const* d_in, const int* in_sizes, int n_in,
                              void* d_out, int out_size, void* d_ws, size_t ws_size,
                              hipStream_t stream) {
    (void)in_sizes; (void)n_in; (void)out_size; (void)ws_size;
    const float* emb = (const float*)d_in[0];
    const float* Wq  = (const float*)d_in[1];
    const float* Wk  = (const float*)d_in[2];
    const float* Wv  = (const float*)d_in[3];
    const float* Wo  = (const float*)d_in[4];
    const float* W1  = (const float*)d_in[5];
    const float* b1  = (const float*)d_in[6];
    const float* W2  = (const float*)d_in[7];
    const float* b2  = (const float*)d_in[8];
    const float* g1  = (const float*)d_in[9];
    const float* be1 = (const float*)d_in[10];
    const float* g2  = (const float*)d_in[11];
    const float* be2 = (const float*)d_in[12];
    float* out = (float*)d_out;

    // ws layout (bf16 elems; ME = 1M elems = 2MB). Total 36 ME = 72 MB.
    __bf16* wsb = (__bf16*)d_ws;
    const size_t ME = 1024 * 1024;
    __bf16* h     = wsb;
    __bf16* qkv   = wsb + 4 * ME;
    __bf16* ctx   = wsb;
    __bf16* ff1   = wsb;
    __bf16* h2    = wsb + 16 * ME;
    __bf16* BtQKV = wsb + 20 * ME;
    __bf16* BtO   = wsb + 23 * ME;
    __bf16* Bt1   = wsb + 24 * ME;
    __bf16* Bt2   = wsb + 28 * ME;
    __bf16* Vt    = wsb + 32 * ME;
    __bf16* woP   = wsb + 4 * ME;    // 2 x 4 ME
    __bf16* w2P0  = wsb + 16 * ME;   // z0..z2 contiguous (12 ME)
    __bf16* w2P3  = wsb + 32 * ME;   // z3

    prep_all<<<16384, 256, 0, stream>>>(Wq, Wk, Wv, Wo, W1, W2,
                                        BtQKV, BtO, Bt1, Bt2,
                                        emb, g1, be1, h);

    mgemm256_qkv<<<dim3(16, 12), 512, 0, stream>>>(h, BtQKV, qkv, Vt);

    attn_mfma<<<dim3(32, 32), 256, 0, stream>>>(qkv, Vt, ctx);

    // Wo split-K x2 on the legacy 128-tile core, bf16 partials
    mgemm_sk<<<dim3(32, 8, 2), 256, 0, stream>>>(
        ctx, BtO, woP, nullptr, ROWS, 1024, 1024, 512);
    red_wo_ln<<<ROWS, 256, 0, stream>>>(emb, woP, woP + 4 * ME, g2, be2, out, h2);

    mgemm256<true, true><<<dim3(16, 16), 512, 0, stream>>>(
        h2, Bt1, b1, ff1, 4096, 1024);

    // W2 split-K x4 on the 256-tile core, bf16 partials
    mgemm256_sk<1024><<<dim3(16, 4, 4), 512, 0, stream>>>(
        ff1, Bt2, w2P0, w2P3, ROWS, 1024, 4096);
    red_w2<<<2048, 256, 0, stream>>>(w2P0, w2P3, b2, out, 1024);
}